// Round 7
// baseline (184.432 us; speedup 1.0000x reference)
//
#include <hip/hip_runtime.h>
#include <math.h>

#define TSIZE (1u << 20)
#define PRIME_Y 2654435761u
#define NHASH 6   // hashed levels 6..11

typedef __attribute__((ext_vector_type(8))) short short8;     // bf16x8 MFMA frag
typedef __attribute__((ext_vector_type(4))) float f32x4;      // MFMA acc frag
typedef __attribute__((ext_vector_type(4))) float float4v;
typedef __attribute__((ext_vector_type(4))) unsigned uint4v;
typedef __attribute__((ext_vector_type(2))) unsigned uint2v;

struct alignas(8) f4a8 { float x, y, z, w; };   // 16B row load at 8B alignment

__device__ __forceinline__ unsigned bf16rne(unsigned u) {
    return (u + 0x7fffu + ((u >> 16) & 1u)) >> 16;   // RNE to bf16 (in low 16)
}
__device__ __forceinline__ unsigned pack_bf16x2(float a, float b) {
    return (bf16rne(__float_as_uint(a)) & 0xffffu) | (bf16rne(__float_as_uint(b)) << 16);
}
__device__ __forceinline__ float2 unpack_bf16x2(unsigned u) {
    float2 r;
    r.x = __uint_as_float(u << 16);
    r.y = __uint_as_float(u & 0xffff0000u);
    return r;
}
__device__ __forceinline__ short f2bf(float x) {
    return (short)(bf16rne(__float_as_uint(x)) & 0xffffu);
}
__device__ __forceinline__ float bf2f(short h) {
    return __uint_as_float(((unsigned)(unsigned short)h) << 16);
}

// ---- pass 0: convert hashed tables f32->bf16x2 in ws; block 0 also builds
// the per-lane MFMA B-fragments (setup folded in to save a dispatch).
__global__ __launch_bounds__(256) void convert_kernel(
    const float* __restrict__ table, unsigned* __restrict__ wtab,
    const float* __restrict__ W0, const float* __restrict__ b0,
    const float* __restrict__ W1, const float* __restrict__ b1,
    const float* __restrict__ W2, const float* __restrict__ b2,
    const float* __restrict__ W3,
    uint4v* __restrict__ wfrag)
{
    if (blockIdx.x == 0 && threadIdx.x < 64) {
        const int lane = threadIdx.x;
        const int n = lane & 15;
        const int kb = lane >> 4;
        short8 bf0, b1a, b1b, b2a, b2b;
        #pragma unroll
        for (int j = 0; j < 8; ++j) {
            const int k = kb * 8 + j;
            bf0[j] = (k < 24) ? f2bf(W0[k * 16 + n]) : (short)0;
            const int i = k >> 1;
            const float w1 = W1[i * 16 + n];
            const float w2 = W2[i * 16 + n];
            const short w1h = f2bf(w1), w2h = f2bf(w2);
            b1a[j] = w1h;
            b2a[j] = w2h;
            b1b[j] = (k & 1) ? (short)0 : f2bf(w1 - bf2f(w1h));
            b2b[j] = (k & 1) ? (short)0 : f2bf(w2 - bf2f(w2h));
        }
        union { short8 s; uint4v u; } cv;
        cv.s = bf0; wfrag[0 * 64 + lane] = cv.u;
        cv.s = b1a; wfrag[1 * 64 + lane] = cv.u;
        cv.s = b1b; wfrag[2 * 64 + lane] = cv.u;
        cv.s = b2a; wfrag[3 * 64 + lane] = cv.u;
        cv.s = b2b; wfrag[4 * 64 + lane] = cv.u;
        float4v bb;
        bb.x = b0[n]; bb.y = b1[n]; bb.z = b2[n]; bb.w = W3[n];
        union { float4v f; uint4v u; } cf; cf.f = bb;
        wfrag[5 * 64 + lane] = cf.u;
    }
    const size_t total4 = (size_t)NHASH * TSIZE / 2;   // float4 chunks (2 entries)
    const float4v* __restrict__ src =
        reinterpret_cast<const float4v*>(table + (size_t)6 * TSIZE * 2);
    uint2v* __restrict__ dst = reinterpret_cast<uint2v*>(wtab);
    for (size_t i = (size_t)blockIdx.x * 256 + threadIdx.x; i < total4;
         i += (size_t)gridDim.x * 256) {
        float4v v = __builtin_nontemporal_load(&src[i]);
        uint2v o;
        o.x = pack_bf16x2(v.x, v.y);
        o.y = pack_bf16x2(v.z, v.w);
        __builtin_nontemporal_store(o, &dst[i]);
    }
}

// ---- dense pass: levels 0..5 (tables total 2.8 MB -> all L2-resident in one
// pass), 2 points/thread, one 16B row load covers both x-corners.
// Writes bf16 enc streams 0..5 (same RNE bits the mlp used to produce).
__global__ __launch_bounds__(256) void dense_kernel(const float* __restrict__ coords,
                                                    const float* __restrict__ table,
                                                    unsigned* __restrict__ wenc,
                                                    int N) {
    const int gid = blockIdx.x * 256 + threadIdx.x;
    const int base2 = gid * 2;
    if (base2 >= N) return;

    if (base2 + 1 < N) {
        const float4v cc = reinterpret_cast<const float4v*>(coords)[gid];
        const float xs[2] = {cc.x, cc.z};
        const float ys[2] = {cc.y, cc.w};
        unsigned ow[6][2];
        #pragma unroll
        for (int lvl = 0; lvl < 6; ++lvl) {
            const int res = 16 << lvl;
            const int stride = res + 1;
            const float* __restrict__ tl = table + (size_t)lvl * TSIZE * 2u;
            #pragma unroll
            for (int p = 0; p < 2; ++p) {
                const float px = xs[p] * (float)res;
                const float py = ys[p] * (float)res;
                const float fx = floorf(px), fy = floorf(py);
                const float wx = px - fx, wy = py - fy;
                const int ix = (int)fx, iy = (int)fy;
                const int b = ix + iy * stride;
                const f4a8 r0 = *reinterpret_cast<const f4a8*>(tl + 2 * (size_t)b);
                const f4a8 r1 = *reinterpret_cast<const f4a8*>(tl + 2 * (size_t)(b + stride));
                const float w00 = (1.0f - wx) * (1.0f - wy);
                const float w10 = wx * (1.0f - wy);
                const float w01 = (1.0f - wx) * wy;
                const float w11 = wx * wy;
                ow[lvl][p] = pack_bf16x2(r0.x * w00 + r0.z * w10 + r1.x * w01 + r1.z * w11,
                                         r0.y * w00 + r0.w * w10 + r1.y * w01 + r1.w * w11);
            }
        }
        #pragma unroll
        for (int lvl = 0; lvl < 6; ++lvl) {
            uint2v o; o.x = ow[lvl][0]; o.y = ow[lvl][1];
            __builtin_nontemporal_store(o,
                reinterpret_cast<uint2v*>(wenc + (size_t)lvl * N + base2));
        }
    } else {
        const float2 c = reinterpret_cast<const float2*>(coords)[base2];
        #pragma unroll
        for (int lvl = 0; lvl < 6; ++lvl) {
            const int res = 16 << lvl;
            const int stride = res + 1;
            const float* __restrict__ tl = table + (size_t)lvl * TSIZE * 2u;
            const float px = c.x * (float)res;
            const float py = c.y * (float)res;
            const float fx = floorf(px), fy = floorf(py);
            const float wx = px - fx, wy = py - fy;
            const int b = (int)fx + (int)fy * stride;
            const f4a8 r0 = *reinterpret_cast<const f4a8*>(tl + 2 * (size_t)b);
            const f4a8 r1 = *reinterpret_cast<const f4a8*>(tl + 2 * (size_t)(b + stride));
            const float w00 = (1.0f - wx) * (1.0f - wy);
            const float w10 = wx * (1.0f - wy);
            const float w01 = (1.0f - wx) * wy;
            const float w11 = wx * wy;
            wenc[(size_t)lvl * N + base2] =
                pack_bf16x2(r0.x * w00 + r0.z * w10 + r1.x * w01 + r1.z * w11,
                            r0.y * w00 + r0.w * w10 + r1.y * w01 + r1.w * w11);
        }
    }
}

// ---- per-level hash pass: 4 consecutive points/thread, parity pair loads.
// Writes enc stream 6+lvl.
__global__ __launch_bounds__(256) void pass_kernel(const float* __restrict__ coords,
                                                   const unsigned* __restrict__ wtab,
                                                   unsigned* __restrict__ wenc,
                                                   int lvl, int N) {
    const int gid = blockIdx.x * 256 + threadIdx.x;
    const int base = gid * 4;
    if (base >= N) return;
    const int res = 16 << (lvl + 6);
    const unsigned* __restrict__ tl = wtab + (size_t)lvl * TSIZE;
    const uint2v* __restrict__ tl2 = reinterpret_cast<const uint2v*>(tl);
    unsigned* __restrict__ we = wenc + (size_t)(6 + lvl) * N;

    if (base + 3 < N) {
        const float4v* __restrict__ c4 = reinterpret_cast<const float4v*>(coords);
        const float4v ca = c4[gid * 2];
        const float4v cb = c4[gid * 2 + 1];
        const float xs[4] = {ca.x, ca.z, cb.x, cb.z};
        const float ys[4] = {ca.y, ca.w, cb.y, cb.w};
        unsigned h00a[4], h01a[4], h10a[4], h11a[4], oddp[4];
        float wxs[4], wys[4];
        #pragma unroll
        for (int p = 0; p < 4; ++p) {
            const float px = xs[p] * (float)res;
            const float py = ys[p] * (float)res;
            const float fx = floorf(px), fy = floorf(py);
            wxs[p] = px - fx;
            wys[p] = py - fy;
            const unsigned ux = (unsigned)(int)fx, uy = (unsigned)(int)fy;
            const unsigned hy0 = uy * PRIME_Y;
            const unsigned hy1 = (uy + 1u) * PRIME_Y;
            h00a[p] = (ux ^ hy0) & (TSIZE - 1u);
            h01a[p] = (ux ^ hy1) & (TSIZE - 1u);
            h10a[p] = ((ux + 1u) ^ hy0) & (TSIZE - 1u);
            h11a[p] = ((ux + 1u) ^ hy1) & (TSIZE - 1u);
            oddp[p] = ux & 1u;
        }
        uint2v pr0[4], pr1[4];
        #pragma unroll
        for (int p = 0; p < 4; ++p) {
            pr0[p] = tl2[h00a[p] >> 1];
            pr1[p] = tl2[h01a[p] >> 1];
        }
        unsigned t10[4], t11[4];
        #pragma unroll
        for (int p = 0; p < 4; ++p) { t10[p] = 0u; t11[p] = 0u; }
        #pragma unroll
        for (int p = 0; p < 4; ++p) {
            if (oddp[p]) {
                t10[p] = tl[h10a[p]];
                t11[p] = tl[h11a[p]];
            }
        }
        uint4v r;
        #pragma unroll
        for (int p = 0; p < 4; ++p) {
            const unsigned s0 = h00a[p] & 1u;
            const unsigned s1 = h01a[p] & 1u;
            const unsigned v00 = s0 ? pr0[p].y : pr0[p].x;
            const unsigned v01 = s1 ? pr1[p].y : pr1[p].x;
            const unsigned v10 = oddp[p] ? t10[p] : (s0 ? pr0[p].x : pr0[p].y);
            const unsigned v11 = oddp[p] ? t11[p] : (s1 ? pr1[p].x : pr1[p].y);
            const float wx = wxs[p], wy = wys[p];
            const float w00 = (1.0f - wx) * (1.0f - wy);
            const float w10 = wx * (1.0f - wy);
            const float w01 = (1.0f - wx) * wy;
            const float w11 = wx * wy;
            const float2 f00 = unpack_bf16x2(v00);
            const float2 f10 = unpack_bf16x2(v10);
            const float2 f01 = unpack_bf16x2(v01);
            const float2 f11 = unpack_bf16x2(v11);
            const float e0 = f00.x * w00 + f10.x * w10 + f01.x * w01 + f11.x * w11;
            const float e1 = f00.y * w00 + f10.y * w10 + f01.y * w01 + f11.y * w11;
            r[p] = pack_bf16x2(e0, e1);
        }
        __builtin_nontemporal_store(r, &((uint4v*)we)[gid]);
    } else {
        for (int p = 0; p < 4 && base + p < N; ++p) {
            const float2 c = reinterpret_cast<const float2*>(coords)[base + p];
            const float px = c.x * (float)res;
            const float py = c.y * (float)res;
            const float fx = floorf(px), fy = floorf(py);
            const float wx = px - fx, wy = py - fy;
            const unsigned ux = (unsigned)(int)fx, uy = (unsigned)(int)fy;
            const unsigned hy0 = uy * PRIME_Y;
            const unsigned hy1 = (uy + 1u) * PRIME_Y;
            const float2 v00 = unpack_bf16x2(tl[(ux ^ hy0) & (TSIZE - 1u)]);
            const float2 v10 = unpack_bf16x2(tl[((ux + 1u) ^ hy0) & (TSIZE - 1u)]);
            const float2 v01 = unpack_bf16x2(tl[(ux ^ hy1) & (TSIZE - 1u)]);
            const float2 v11 = unpack_bf16x2(tl[((ux + 1u) ^ hy1) & (TSIZE - 1u)]);
            const float w00 = (1.0f - wx) * (1.0f - wy);
            const float w10 = wx * (1.0f - wy);
            const float w01 = (1.0f - wx) * wy;
            const float w11 = wx * wy;
            const float e0 = v00.x * w00 + v10.x * w10 + v01.x * w01 + v11.x * w11;
            const float e1 = v00.y * w00 + v10.y * w10 + v01.y * w01 + v11.y * w11;
            we[base + p] = pack_bf16x2(e0, e1);
        }
    }
}

// ---- final: pure-streaming MFMA SIREN MLP. Reads 12 coalesced enc streams,
// zero gathers. 256 threads = 4 waves, each with its own LDS region.
__global__ __launch_bounds__(256) void mlp_kernel(
    const unsigned* __restrict__ wenc,
    const uint4v* __restrict__ wfrag,
    const float* __restrict__ b3p,
    float* __restrict__ out, int N)
{
    __shared__ char lds[20480];             // 4 waves * 64 rows * 80 B
    const int t = threadIdx.x;
    const int lane = t & 63;
    const int wv = t >> 6;
    const int n = lane & 15;
    const int kb = lane >> 4;
    char* ldsw = lds + wv * 5120;

    // B-fragments: 6 coalesced b128 loads (built once by convert_kernel)
    union { short8 s; uint4v u; } c0, c1, c2, c3, c4;
    c0.u = wfrag[0 * 64 + lane];
    c1.u = wfrag[1 * 64 + lane];
    c2.u = wfrag[2 * 64 + lane];
    c3.u = wfrag[3 * 64 + lane];
    c4.u = wfrag[4 * 64 + lane];
    const short8 bf0 = c0.s, b1a = c1.s, b1b = c2.s, b2a = c3.s, b2b = c4.s;
    union { float4v f; uint4v u; } cf;
    cf.u = wfrag[5 * 64 + lane];
    const float b0n = cf.f.x, b1n = cf.f.y, b2n = cf.f.z, w3n = cf.f.w;
    const float b3s = b3p[0];

    const int idx = blockIdx.x * 256 + t;
    const int idxc = (idx < N) ? idx : (N - 1);

    // 12 coalesced streaming enc loads -> words go straight into the A-layout
    unsigned u[12];
    #pragma unroll
    for (int l = 0; l < 12; ++l)
        u[l] = __builtin_nontemporal_load(&wenc[(size_t)l * N + idxc]);

    {
        uint4v* rowp = (uint4v*)(ldsw + lane * 80);
        uint4v r0; r0.x = u[0]; r0.y = u[1]; r0.z = u[2]; r0.w = u[3];
        uint4v r1; r1.x = u[4]; r1.y = u[5]; r1.z = u[6]; r1.w = u[7];
        uint4v r2; r2.x = u[8]; r2.y = u[9]; r2.z = u[10]; r2.w = u[11];
        uint4v r3; r3.x = 0u; r3.y = 0u; r3.z = 0u; r3.w = 0u;  // keep: no NaN*0
        rowp[0] = r0; rowp[1] = r1; rowp[2] = r2; rowp[3] = r3;
    }
    __syncthreads();

    short8 a[4];
    #pragma unroll
    for (int m = 0; m < 4; ++m)
        a[m] = *(const short8*)(ldsw + (m * 16 + n) * 80 + kb * 16);
    __syncthreads();

    const f32x4 z = {0.f, 0.f, 0.f, 0.f};
    f32x4 acc[4];
    #pragma unroll
    for (int m = 0; m < 4; ++m)
        acc[m] = __builtin_amdgcn_mfma_f32_16x16x32_bf16(a[m], bf0, z, 0, 0, 0);

    unsigned* hp32 = (unsigned*)ldsw;   // rows of 20 words; word n = {hi_n | lo_n<<16}

    // ---- layer 1: h0 = sin(300*(acc+b0)); packed hi|lo write; mfma hi+lo
    #pragma unroll
    for (int m = 0; m < 4; ++m) {
        #pragma unroll
        for (int r = 0; r < 4; ++r) {
            const float v = __sinf(300.0f * (acc[m][r] + b0n));
            const short hi = f2bf(v);
            const short lo = f2bf(v - bf2f(hi));
            const int row = m * 16 + kb * 4 + r;
            hp32[row * 20 + n] =
                ((unsigned)(unsigned short)hi) | (((unsigned)(unsigned short)lo) << 16);
        }
    }
    __syncthreads();
    #pragma unroll
    for (int m = 0; m < 4; ++m)
        a[m] = *(const short8*)(ldsw + (m * 16 + n) * 80 + kb * 16);
    __syncthreads();
    #pragma unroll
    for (int m = 0; m < 4; ++m) {
        f32x4 p = __builtin_amdgcn_mfma_f32_16x16x32_bf16(a[m], b1a, z, 0, 0, 0);
        acc[m] = __builtin_amdgcn_mfma_f32_16x16x32_bf16(a[m], b1b, p, 0, 0, 0);
    }

    // ---- layer 2
    #pragma unroll
    for (int m = 0; m < 4; ++m) {
        #pragma unroll
        for (int r = 0; r < 4; ++r) {
            const float v = __sinf(acc[m][r] + b1n);
            const short hi = f2bf(v);
            const short lo = f2bf(v - bf2f(hi));
            const int row = m * 16 + kb * 4 + r;
            hp32[row * 20 + n] =
                ((unsigned)(unsigned short)hi) | (((unsigned)(unsigned short)lo) << 16);
        }
    }
    __syncthreads();
    #pragma unroll
    for (int m = 0; m < 4; ++m)
        a[m] = *(const short8*)(ldsw + (m * 16 + n) * 80 + kb * 16);
    __syncthreads();
    #pragma unroll
    for (int m = 0; m < 4; ++m) {
        f32x4 p = __builtin_amdgcn_mfma_f32_16x16x32_bf16(a[m], b2a, z, 0, 0, 0);
        acc[m] = __builtin_amdgcn_mfma_f32_16x16x32_bf16(a[m], b2b, p, 0, 0, 0);
    }

    // ---- layer 3 (final, 16->1) in f32: h2 = sin(acc+b2); o = h2@W3 + b3
    float red[4][4];
    #pragma unroll
    for (int m = 0; m < 4; ++m) {
        #pragma unroll
        for (int r = 0; r < 4; ++r) {
            float v = __sinf(acc[m][r] + b2n) * w3n;
            v += __shfl_xor(v, 1);
            v += __shfl_xor(v, 2);
            v += __shfl_xor(v, 4);
            v += __shfl_xor(v, 8);
            red[m][r] = v;     // identical across the 16 lanes of group kb
        }
    }
    const int m2 = n >> 2, r2 = n & 3;
    float ov = 0.f;
    #pragma unroll
    for (int m = 0; m < 4; ++m) {
        #pragma unroll
        for (int r = 0; r < 4; ++r)
            if (m == m2 && r == r2) ov = red[m][r];   // static idx -> cndmask
    }
    const int gidx = blockIdx.x * 256 + wv * 64 + m2 * 16 + kb * 4 + r2;
    if (gidx < N) out[gidx] = ov + b3s;
}

// ---- fallback: R1 fused kernel (known-good) for small ws
__global__ __launch_bounds__(256) void hashsiren_fused(
    const float* __restrict__ coords,
    const float* __restrict__ table,
    const float* __restrict__ W0, const float* __restrict__ b0,
    const float* __restrict__ W1, const float* __restrict__ b1,
    const float* __restrict__ W2, const float* __restrict__ b2,
    const float* __restrict__ W3, const float* __restrict__ b3,
    float* __restrict__ out, int N)
{
    __shared__ float sW0[384];
    __shared__ float sW1[256];
    __shared__ float sW2[256];
    __shared__ float sb0[16], sb1[16], sb2[16], sW3[16];
    __shared__ float sb3;

    const int t = threadIdx.x;
    for (int i = t; i < 384; i += 256) sW0[i] = W0[i];
    sW1[t] = W1[t];
    sW2[t] = W2[t];
    if (t < 16) { sb0[t] = b0[t]; sb1[t] = b1[t]; sb2[t] = b2[t]; sW3[t] = W3[t]; }
    if (t == 0) sb3 = b3[0];
    __syncthreads();

    const int idx = blockIdx.x * 256 + t;
    if (idx >= N) return;

    const float2 c = reinterpret_cast<const float2*>(coords)[idx];

    float2 hv00[6], hv10[6], hv01[6], hv11[6];
    float hwx[6], hwy[6];
    #pragma unroll
    for (int l = 0; l < 6; ++l) {
        const int res = 16 << (l + 6);
        const float px = c.x * (float)res;
        const float py = c.y * (float)res;
        const float fx = floorf(px), fy = floorf(py);
        hwx[l] = px - fx;
        hwy[l] = py - fy;
        const unsigned ux = (unsigned)(int)fx, uy = (unsigned)(int)fy;
        const unsigned hy0 = uy * PRIME_Y;
        const unsigned hy1 = (uy + 1u) * PRIME_Y;
        const float2* __restrict__ tl =
            reinterpret_cast<const float2*>(table) + (size_t)(l + 6) * TSIZE;
        hv00[l] = tl[(ux ^ hy0) & (TSIZE - 1u)];
        hv10[l] = tl[((ux + 1u) ^ hy0) & (TSIZE - 1u)];
        hv01[l] = tl[(ux ^ hy1) & (TSIZE - 1u)];
        hv11[l] = tl[((ux + 1u) ^ hy1) & (TSIZE - 1u)];
    }

    float enc[24];
    #pragma unroll
    for (int lvl = 0; lvl < 6; ++lvl) {
        const int res = 16 << lvl;
        const float px = c.x * (float)res;
        const float py = c.y * (float)res;
        const float fx = floorf(px), fy = floorf(py);
        const float wx = px - fx, wy = py - fy;
        const int ix = (int)fx, iy = (int)fy;
        const int stride = res + 1;
        const int base = ix + iy * stride;
        const float2* __restrict__ tl =
            reinterpret_cast<const float2*>(table) + (size_t)lvl * TSIZE;
        const float2 v00 = tl[base];
        const float2 v10 = tl[base + 1];
        const float2 v01 = tl[base + stride];
        const float2 v11 = tl[base + stride + 1];
        const float w00 = (1.0f - wx) * (1.0f - wy);
        const float w10 = wx * (1.0f - wy);
        const float w01 = (1.0f - wx) * wy;
        const float w11 = wx * wy;
        enc[2 * lvl]     = v00.x * w00 + v10.x * w10 + v01.x * w01 + v11.x * w11;
        enc[2 * lvl + 1] = v00.y * w00 + v10.y * w10 + v01.y * w01 + v11.y * w11;
    }
    #pragma unroll
    for (int l = 0; l < 6; ++l) {
        const float wx = hwx[l], wy = hwy[l];
        const float w00 = (1.0f - wx) * (1.0f - wy);
        const float w10 = wx * (1.0f - wy);
        const float w01 = (1.0f - wx) * wy;
        const float w11 = wx * wy;
        enc[2 * (l + 6)]     = hv00[l].x * w00 + hv10[l].x * w10 + hv01[l].x * w01 + hv11[l].x * w11;
        enc[2 * (l + 6) + 1] = hv00[l].y * w00 + hv10[l].y * w10 + hv01[l].y * w01 + hv11[l].y * w11;
    }

    float h0[16];
    #pragma unroll
    for (int j = 0; j < 16; ++j) {
        float aa = sb0[j];
        #pragma unroll
        for (int k = 0; k < 24; ++k) aa += enc[k] * sW0[k * 16 + j];
        h0[j] = __sinf(300.0f * aa);
    }
    float h1[16];
    #pragma unroll
    for (int j = 0; j < 16; ++j) {
        float aa = sb1[j];
        #pragma unroll
        for (int k = 0; k < 16; ++k) aa += h0[k] * sW1[k * 16 + j];
        h1[j] = __sinf(aa);
    }
    float h2[16];
    #pragma unroll
    for (int j = 0; j < 16; ++j) {
        float aa = sb2[j];
        #pragma unroll
        for (int k = 0; k < 16; ++k) aa += h1[k] * sW2[k * 16 + j];
        h2[j] = __sinf(aa);
    }
    float o = sb3;
    #pragma unroll
    for (int k = 0; k < 16; ++k) o += h2[k] * sW3[k];
    out[idx] = o;
}

extern "C" void kernel_launch(void* const* d_in, const int* in_sizes, int n_in,
                              void* d_out, int out_size, void* d_ws, size_t ws_size,
                              hipStream_t stream) {
    const float* coords = (const float*)d_in[0];
    const float* table  = (const float*)d_in[1];
    const float* W0 = (const float*)d_in[2];
    const float* b0 = (const float*)d_in[3];
    const float* W1 = (const float*)d_in[4];
    const float* b1 = (const float*)d_in[5];
    const float* W2 = (const float*)d_in[6];
    const float* b2 = (const float*)d_in[7];
    const float* W3 = (const float*)d_in[8];
    const float* b3 = (const float*)d_in[9];
    float* out = (float*)d_out;

    const int N = in_sizes[0] / 2;  // coords is [N,2]

    const size_t tab_w = (size_t)NHASH * TSIZE;          // u32 words
    const size_t enc_w = (size_t)12 * (size_t)N;         // u32 words (12 streams)
    const size_t need = tab_w * 4 + enc_w * 4 + 6144;    // + wfrag
    if (ws_size >= need) {
        unsigned* wtab = (unsigned*)d_ws;
        unsigned* wenc = wtab + tab_w;
        uint4v* wfrag = (uint4v*)(wenc + enc_w);
        convert_kernel<<<4096, 256, 0, stream>>>(table, wtab,
                                                 W0, b0, W1, b1, W2, b2, W3, wfrag);
        dense_kernel<<<(N / 2 + 255) / 256, 256, 0, stream>>>(coords, table, wenc, N);
        const int pgrid = (N + 1023) / 1024;
        for (int l = 0; l < NHASH; ++l)
            pass_kernel<<<pgrid, 256, 0, stream>>>(coords, wtab, wenc, l, N);
        mlp_kernel<<<(N + 255) / 256, 256, 0, stream>>>(wenc, wfrag, b3, out, N);
    } else {
        const int block = 256;
        const int grid = (N + block - 1) / block;
        hashsiren_fused<<<grid, block, 0, stream>>>(coords, table,
                                                    W0, b0, W1, b1, W2, b2, W3, b3,
                                                    out, N);
    }
}

// Round 9
// 179.583 us; speedup vs baseline: 1.0270x; 1.0270x over previous
//
#include <hip/hip_runtime.h>
#include <math.h>

#define TSIZE (1u << 20)
#define PRIME_Y 2654435761u
#define NHASH 6   // hashed levels 6..11

typedef __attribute__((ext_vector_type(8))) short short8;     // bf16x8 MFMA frag
typedef __attribute__((ext_vector_type(4))) float f32x4;      // MFMA acc frag
typedef __attribute__((ext_vector_type(4))) float float4v;
typedef __attribute__((ext_vector_type(2))) float float2v;
typedef __attribute__((ext_vector_type(4))) unsigned uint4v;
typedef __attribute__((ext_vector_type(2))) unsigned uint2v;

struct alignas(8) f4a8 { float x, y, z, w; };   // 16B row load at 8B alignment

__device__ __forceinline__ unsigned bf16rne(unsigned u) {
    return (u + 0x7fffu + ((u >> 16) & 1u)) >> 16;   // RNE to bf16 (in low 16)
}
__device__ __forceinline__ unsigned pack_bf16x2(float a, float b) {
    return (bf16rne(__float_as_uint(a)) & 0xffffu) | (bf16rne(__float_as_uint(b)) << 16);
}
__device__ __forceinline__ float2 unpack_bf16x2(unsigned u) {
    float2 r;
    r.x = __uint_as_float(u << 16);
    r.y = __uint_as_float(u & 0xffff0000u);
    return r;
}
__device__ __forceinline__ short f2bf(float x) {
    return (short)(bf16rne(__float_as_uint(x)) & 0xffffu);
}
__device__ __forceinline__ float bf2f(short h) {
    return __uint_as_float(((unsigned)(unsigned short)h) << 16);
}

// ---- pass 0: convert hashed tables f32->bf16x2 in ws; block 0 also builds
// the per-lane MFMA B-fragments.
__global__ __launch_bounds__(256) void convert_kernel(
    const float* __restrict__ table, unsigned* __restrict__ wtab,
    const float* __restrict__ W0, const float* __restrict__ b0,
    const float* __restrict__ W1, const float* __restrict__ b1,
    const float* __restrict__ W2, const float* __restrict__ b2,
    const float* __restrict__ W3,
    uint4v* __restrict__ wfrag)
{
    if (blockIdx.x == 0 && threadIdx.x < 64) {
        const int lane = threadIdx.x;
        const int n = lane & 15;
        const int kb = lane >> 4;
        short8 bf0, b1a, b1b, b2a, b2b;
        #pragma unroll
        for (int j = 0; j < 8; ++j) {
            const int k = kb * 8 + j;
            bf0[j] = (k < 24) ? f2bf(W0[k * 16 + n]) : (short)0;
            const int i = k >> 1;
            const float w1 = W1[i * 16 + n];
            const float w2 = W2[i * 16 + n];
            const short w1h = f2bf(w1), w2h = f2bf(w2);
            b1a[j] = w1h;
            b2a[j] = w2h;
            b1b[j] = (k & 1) ? (short)0 : f2bf(w1 - bf2f(w1h));
            b2b[j] = (k & 1) ? (short)0 : f2bf(w2 - bf2f(w2h));
        }
        union { short8 s; uint4v u; } cv;
        cv.s = bf0; wfrag[0 * 64 + lane] = cv.u;
        cv.s = b1a; wfrag[1 * 64 + lane] = cv.u;
        cv.s = b1b; wfrag[2 * 64 + lane] = cv.u;
        cv.s = b2a; wfrag[3 * 64 + lane] = cv.u;
        cv.s = b2b; wfrag[4 * 64 + lane] = cv.u;
        float4v bb;
        bb.x = b0[n]; bb.y = b1[n]; bb.z = b2[n]; bb.w = W3[n];
        union { float4v f; uint4v u; } cf; cf.f = bb;
        wfrag[5 * 64 + lane] = cf.u;
    }
    const size_t total4 = (size_t)NHASH * TSIZE / 2;   // float4 chunks (2 entries)
    const float4v* __restrict__ src =
        reinterpret_cast<const float4v*>(table + (size_t)6 * TSIZE * 2);
    uint2v* __restrict__ dst = reinterpret_cast<uint2v*>(wtab);
    for (size_t i = (size_t)blockIdx.x * 256 + threadIdx.x; i < total4;
         i += (size_t)gridDim.x * 256) {
        float4v v = __builtin_nontemporal_load(&src[i]);
        uint2v o;
        o.x = pack_bf16x2(v.x, v.y);
        o.y = pack_bf16x2(v.z, v.w);
        __builtin_nontemporal_store(o, &dst[i]);
    }
}

// ---- per-level hash pass: 4 consecutive points/thread, parity pair loads.
// Coords are nontemporal (streaming) so they do NOT evict the 4 MiB table
// from L2 — the table is the only L2-resident data in this pass.
__global__ __launch_bounds__(256) void pass_kernel(const float* __restrict__ coords,
                                                   const unsigned* __restrict__ wtab,
                                                   unsigned* __restrict__ wenc,
                                                   int lvl, int N) {
    const int gid = blockIdx.x * 256 + threadIdx.x;
    const int base = gid * 4;
    if (base >= N) return;
    const int res = 16 << (lvl + 6);
    const unsigned* __restrict__ tl = wtab + (size_t)lvl * TSIZE;
    const uint2v* __restrict__ tl2 = reinterpret_cast<const uint2v*>(tl);
    unsigned* __restrict__ we = wenc + (size_t)lvl * N;

    if (base + 3 < N) {
        const float4v* __restrict__ c4 = reinterpret_cast<const float4v*>(coords);
        const float4v ca = __builtin_nontemporal_load(&c4[gid * 2]);
        const float4v cb = __builtin_nontemporal_load(&c4[gid * 2 + 1]);
        const float xs[4] = {ca.x, ca.z, cb.x, cb.z};
        const float ys[4] = {ca.y, ca.w, cb.y, cb.w};
        unsigned h00a[4], h01a[4], h10a[4], h11a[4], oddp[4];
        float wxs[4], wys[4];
        #pragma unroll
        for (int p = 0; p < 4; ++p) {
            const float px = xs[p] * (float)res;
            const float py = ys[p] * (float)res;
            const float fx = floorf(px), fy = floorf(py);
            wxs[p] = px - fx;
            wys[p] = py - fy;
            const unsigned ux = (unsigned)(int)fx, uy = (unsigned)(int)fy;
            const unsigned hy0 = uy * PRIME_Y;
            const unsigned hy1 = (uy + 1u) * PRIME_Y;
            h00a[p] = (ux ^ hy0) & (TSIZE - 1u);
            h01a[p] = (ux ^ hy1) & (TSIZE - 1u);
            h10a[p] = ((ux + 1u) ^ hy0) & (TSIZE - 1u);
            h11a[p] = ((ux + 1u) ^ hy1) & (TSIZE - 1u);
            oddp[p] = ux & 1u;
        }
        uint2v pr0[4], pr1[4];
        #pragma unroll
        for (int p = 0; p < 4; ++p) {
            pr0[p] = tl2[h00a[p] >> 1];
            pr1[p] = tl2[h01a[p] >> 1];
        }
        unsigned t10[4], t11[4];
        #pragma unroll
        for (int p = 0; p < 4; ++p) { t10[p] = 0u; t11[p] = 0u; }
        #pragma unroll
        for (int p = 0; p < 4; ++p) {
            if (oddp[p]) {
                t10[p] = tl[h10a[p]];
                t11[p] = tl[h11a[p]];
            }
        }
        uint4v r;
        #pragma unroll
        for (int p = 0; p < 4; ++p) {
            const unsigned s0 = h00a[p] & 1u;
            const unsigned s1 = h01a[p] & 1u;
            const unsigned v00 = s0 ? pr0[p].y : pr0[p].x;
            const unsigned v01 = s1 ? pr1[p].y : pr1[p].x;
            const unsigned v10 = oddp[p] ? t10[p] : (s0 ? pr0[p].x : pr0[p].y);
            const unsigned v11 = oddp[p] ? t11[p] : (s1 ? pr1[p].x : pr1[p].y);
            const float wx = wxs[p], wy = wys[p];
            const float w00 = (1.0f - wx) * (1.0f - wy);
            const float w10 = wx * (1.0f - wy);
            const float w01 = (1.0f - wx) * wy;
            const float w11 = wx * wy;
            const float2 f00 = unpack_bf16x2(v00);
            const float2 f10 = unpack_bf16x2(v10);
            const float2 f01 = unpack_bf16x2(v01);
            const float2 f11 = unpack_bf16x2(v11);
            const float e0 = f00.x * w00 + f10.x * w10 + f01.x * w01 + f11.x * w11;
            const float e1 = f00.y * w00 + f10.y * w10 + f01.y * w01 + f11.y * w11;
            r[p] = pack_bf16x2(e0, e1);
        }
        __builtin_nontemporal_store(r, &((uint4v*)we)[gid]);
    } else {
        for (int p = 0; p < 4 && base + p < N; ++p) {
            const float2 c = reinterpret_cast<const float2*>(coords)[base + p];
            const float px = c.x * (float)res;
            const float py = c.y * (float)res;
            const float fx = floorf(px), fy = floorf(py);
            const float wx = px - fx, wy = py - fy;
            const unsigned ux = (unsigned)(int)fx, uy = (unsigned)(int)fy;
            const unsigned hy0 = uy * PRIME_Y;
            const unsigned hy1 = (uy + 1u) * PRIME_Y;
            const float2 v00 = unpack_bf16x2(tl[(ux ^ hy0) & (TSIZE - 1u)]);
            const float2 v10 = unpack_bf16x2(tl[((ux + 1u) ^ hy0) & (TSIZE - 1u)]);
            const float2 v01 = unpack_bf16x2(tl[(ux ^ hy1) & (TSIZE - 1u)]);
            const float2 v11 = unpack_bf16x2(tl[((ux + 1u) ^ hy1) & (TSIZE - 1u)]);
            const float w00 = (1.0f - wx) * (1.0f - wy);
            const float w10 = wx * (1.0f - wy);
            const float w01 = (1.0f - wx) * wy;
            const float w11 = wx * wy;
            const float e0 = v00.x * w00 + v10.x * w10 + v01.x * w01 + v11.x * w11;
            const float e1 = v00.y * w00 + v10.y * w10 + v01.y * w01 + v11.y * w11;
            we[base + p] = pack_bf16x2(e0, e1);
        }
    }
}

// ---- final (R6 structure): dense levels (16B row loads, tables L2-cached)
// + hashed enc streams (nt) + MFMA SIREN MLP. 256 threads = 4 waves,
// each wave owns a 5120 B LDS region. Streams (coords/enc/out) are nt so
// the 2.8 MB dense tables stay L2-resident.
__global__ __launch_bounds__(256) void mlp_kernel(
    const float* __restrict__ coords,
    const float* __restrict__ table,
    const unsigned* __restrict__ wenc,
    const uint4v* __restrict__ wfrag,
    const float* __restrict__ b3p,
    float* __restrict__ out, int N)
{
    __shared__ char lds[20480];             // 4 waves * 64 rows * 80 B
    const int t = threadIdx.x;
    const int lane = t & 63;
    const int wv = t >> 6;
    const int n = lane & 15;
    const int kb = lane >> 4;
    char* ldsw = lds + wv * 5120;

    union { short8 s; uint4v u; } c0, c1, c2, c3, c4;
    c0.u = wfrag[0 * 64 + lane];
    c1.u = wfrag[1 * 64 + lane];
    c2.u = wfrag[2 * 64 + lane];
    c3.u = wfrag[3 * 64 + lane];
    c4.u = wfrag[4 * 64 + lane];
    const short8 bf0 = c0.s, b1a = c1.s, b1b = c2.s, b2a = c3.s, b2b = c4.s;
    union { float4v f; uint4v u; } cf;
    cf.u = wfrag[5 * 64 + lane];
    const float b0n = cf.f.x, b1n = cf.f.y, b2n = cf.f.z, w3n = cf.f.w;
    const float b3s = b3p[0];

    const int idx = blockIdx.x * 256 + t;
    const int idxc = (idx < N) ? idx : (N - 1);

    // hashed-enc streaming loads first (stay in flight over dense interp)
    unsigned he[NHASH];
    #pragma unroll
    for (int l = 0; l < NHASH; ++l)
        he[l] = __builtin_nontemporal_load(&wenc[(size_t)l * N + idxc]);

    const float2v cc = __builtin_nontemporal_load(
        reinterpret_cast<const float2v*>(coords) + idxc);

    float enc[24];
    #pragma unroll
    for (int lvl = 0; lvl < 6; ++lvl) {
        const int res = 16 << lvl;
        const float px = cc.x * (float)res;
        const float py = cc.y * (float)res;
        const float fx = floorf(px), fy = floorf(py);
        const float wx = px - fx, wy = py - fy;
        const int ix = (int)fx, iy = (int)fy;
        const int stride = res + 1;
        const int base = ix + iy * stride;
        const float* __restrict__ tl = table + (size_t)lvl * TSIZE * 2u;
        const f4a8 r0 = *reinterpret_cast<const f4a8*>(tl + 2 * (size_t)base);
        const f4a8 r1 = *reinterpret_cast<const f4a8*>(tl + 2 * (size_t)(base + stride));
        const float w00 = (1.0f - wx) * (1.0f - wy);
        const float w10 = wx * (1.0f - wy);
        const float w01 = (1.0f - wx) * wy;
        const float w11 = wx * wy;
        enc[2 * lvl]     = r0.x * w00 + r0.z * w10 + r1.x * w01 + r1.z * w11;
        enc[2 * lvl + 1] = r0.y * w00 + r0.w * w10 + r1.y * w01 + r1.w * w11;
    }
    #pragma unroll
    for (int l = 0; l < NHASH; ++l) {
        const float2 v = unpack_bf16x2(he[l]);
        enc[12 + 2 * l]     = v.x;
        enc[12 + 2 * l + 1] = v.y;
    }

    // ---- stage enc as bf16, K padded 24->32, row = lane (80 B stride)
    unsigned u[12];
    #pragma unroll
    for (int k = 0; k < 12; ++k) u[k] = pack_bf16x2(enc[2 * k], enc[2 * k + 1]);
    {
        uint4v* rowp = (uint4v*)(ldsw + lane * 80);
        uint4v r0; r0.x = u[0]; r0.y = u[1]; r0.z = u[2]; r0.w = u[3];
        uint4v r1; r1.x = u[4]; r1.y = u[5]; r1.z = u[6]; r1.w = u[7];
        uint4v r2; r2.x = u[8]; r2.y = u[9]; r2.z = u[10]; r2.w = u[11];
        uint4v r3; r3.x = 0u; r3.y = 0u; r3.z = 0u; r3.w = 0u;  // keep: no NaN*0
        rowp[0] = r0; rowp[1] = r1; rowp[2] = r2; rowp[3] = r3;
    }
    __syncthreads();

    short8 a[4];
    #pragma unroll
    for (int m = 0; m < 4; ++m)
        a[m] = *(const short8*)(ldsw + (m * 16 + n) * 80 + kb * 16);
    __syncthreads();

    const f32x4 z = {0.f, 0.f, 0.f, 0.f};
    f32x4 acc[4];
    #pragma unroll
    for (int m = 0; m < 4; ++m)
        acc[m] = __builtin_amdgcn_mfma_f32_16x16x32_bf16(a[m], bf0, z, 0, 0, 0);

    unsigned* hp32 = (unsigned*)ldsw;   // rows of 20 words; word n = {hi_n | lo_n<<16}

    // ---- layer 1
    #pragma unroll
    for (int m = 0; m < 4; ++m) {
        #pragma unroll
        for (int r = 0; r < 4; ++r) {
            const float v = __sinf(300.0f * (acc[m][r] + b0n));
            const short hi = f2bf(v);
            const short lo = f2bf(v - bf2f(hi));
            const int row = m * 16 + kb * 4 + r;
            hp32[row * 20 + n] =
                ((unsigned)(unsigned short)hi) | (((unsigned)(unsigned short)lo) << 16);
        }
    }
    __syncthreads();
    #pragma unroll
    for (int m = 0; m < 4; ++m)
        a[m] = *(const short8*)(ldsw + (m * 16 + n) * 80 + kb * 16);
    __syncthreads();
    #pragma unroll
    for (int m = 0; m < 4; ++m) {
        f32x4 p = __builtin_amdgcn_mfma_f32_16x16x32_bf16(a[m], b1a, z, 0, 0, 0);
        acc[m] = __builtin_amdgcn_mfma_f32_16x16x32_bf16(a[m], b1b, p, 0, 0, 0);
    }

    // ---- layer 2
    #pragma unroll
    for (int m = 0; m < 4; ++m) {
        #pragma unroll
        for (int r = 0; r < 4; ++r) {
            const float v = __sinf(acc[m][r] + b1n);
            const short hi = f2bf(v);
            const short lo = f2bf(v - bf2f(hi));
            const int row = m * 16 + kb * 4 + r;
            hp32[row * 20 + n] =
                ((unsigned)(unsigned short)hi) | (((unsigned)(unsigned short)lo) << 16);
        }
    }
    __syncthreads();
    #pragma unroll
    for (int m = 0; m < 4; ++m)
        a[m] = *(const short8*)(ldsw + (m * 16 + n) * 80 + kb * 16);
    __syncthreads();
    #pragma unroll
    for (int m = 0; m < 4; ++m) {
        f32x4 p = __builtin_amdgcn_mfma_f32_16x16x32_bf16(a[m], b2a, z, 0, 0, 0);
        acc[m] = __builtin_amdgcn_mfma_f32_16x16x32_bf16(a[m], b2b, p, 0, 0, 0);
    }

    // ---- layer 3 (final, 16->1) in f32
    float red[4][4];
    #pragma unroll
    for (int m = 0; m < 4; ++m) {
        #pragma unroll
        for (int r = 0; r < 4; ++r) {
            float v = __sinf(acc[m][r] + b2n) * w3n;
            v += __shfl_xor(v, 1);
            v += __shfl_xor(v, 2);
            v += __shfl_xor(v, 4);
            v += __shfl_xor(v, 8);
            red[m][r] = v;
        }
    }
    const int m2 = n >> 2, r2 = n & 3;
    float ov = 0.f;
    #pragma unroll
    for (int m = 0; m < 4; ++m) {
        #pragma unroll
        for (int r = 0; r < 4; ++r)
            if (m == m2 && r == r2) ov = red[m][r];
    }
    const int gidx = blockIdx.x * 256 + wv * 64 + m2 * 16 + kb * 4 + r2;
    if (gidx < N) __builtin_nontemporal_store(ov + b3s, &out[gidx]);
}

// ---- fallback: R1 fused kernel (known-good) for small ws
__global__ __launch_bounds__(256) void hashsiren_fused(
    const float* __restrict__ coords,
    const float* __restrict__ table,
    const float* __restrict__ W0, const float* __restrict__ b0,
    const float* __restrict__ W1, const float* __restrict__ b1,
    const float* __restrict__ W2, const float* __restrict__ b2,
    const float* __restrict__ W3, const float* __restrict__ b3,
    float* __restrict__ out, int N)
{
    __shared__ float sW0[384];
    __shared__ float sW1[256];
    __shared__ float sW2[256];
    __shared__ float sb0[16], sb1[16], sb2[16], sW3[16];
    __shared__ float sb3;

    const int t = threadIdx.x;
    for (int i = t; i < 384; i += 256) sW0[i] = W0[i];
    sW1[t] = W1[t];
    sW2[t] = W2[t];
    if (t < 16) { sb0[t] = b0[t]; sb1[t] = b1[t]; sb2[t] = b2[t]; sW3[t] = W3[t]; }
    if (t == 0) sb3 = b3[0];
    __syncthreads();

    const int idx = blockIdx.x * 256 + t;
    if (idx >= N) return;

    const float2 c = reinterpret_cast<const float2*>(coords)[idx];

    float2 hv00[6], hv10[6], hv01[6], hv11[6];
    float hwx[6], hwy[6];
    #pragma unroll
    for (int l = 0; l < 6; ++l) {
        const int res = 16 << (l + 6);
        const float px = c.x * (float)res;
        const float py = c.y * (float)res;
        const float fx = floorf(px), fy = floorf(py);
        hwx[l] = px - fx;
        hwy[l] = py - fy;
        const unsigned ux = (unsigned)(int)fx, uy = (unsigned)(int)fy;
        const unsigned hy0 = uy * PRIME_Y;
        const unsigned hy1 = (uy + 1u) * PRIME_Y;
        const float2* __restrict__ tl =
            reinterpret_cast<const float2*>(table) + (size_t)(l + 6) * TSIZE;
        hv00[l] = tl[(ux ^ hy0) & (TSIZE - 1u)];
        hv10[l] = tl[((ux + 1u) ^ hy0) & (TSIZE - 1u)];
        hv01[l] = tl[(ux ^ hy1) & (TSIZE - 1u)];
        hv11[l] = tl[((ux + 1u) ^ hy1) & (TSIZE - 1u)];
    }

    float enc[24];
    #pragma unroll
    for (int lvl = 0; lvl < 6; ++lvl) {
        const int res = 16 << lvl;
        const float px = c.x * (float)res;
        const float py = c.y * (float)res;
        const float fx = floorf(px), fy = floorf(py);
        const float wx = px - fx, wy = py - fy;
        const int ix = (int)fx, iy = (int)fy;
        const int stride = res + 1;
        const int base = ix + iy * stride;
        const float2* __restrict__ tl =
            reinterpret_cast<const float2*>(table) + (size_t)lvl * TSIZE;
        const float2 v00 = tl[base];
        const float2 v10 = tl[base + 1];
        const float2 v01 = tl[base + stride];
        const float2 v11 = tl[base + stride + 1];
        const float w00 = (1.0f - wx) * (1.0f - wy);
        const float w10 = wx * (1.0f - wy);
        const float w01 = (1.0f - wx) * wy;
        const float w11 = wx * wy;
        enc[2 * lvl]     = v00.x * w00 + v10.x * w10 + v01.x * w01 + v11.x * w11;
        enc[2 * lvl + 1] = v00.y * w00 + v10.y * w10 + v01.y * w01 + v11.y * w11;
    }
    #pragma unroll
    for (int l = 0; l < 6; ++l) {
        const float wx = hwx[l], wy = hwy[l];
        const float w00 = (1.0f - wx) * (1.0f - wy);
        const float w10 = wx * (1.0f - wy);
        const float w01 = (1.0f - wx) * wy;
        const float w11 = wx * wy;
        enc[2 * (l + 6)]     = hv00[l].x * w00 + hv10[l].x * w10 + hv01[l].x * w01 + hv11[l].x * w11;
        enc[2 * (l + 6) + 1] = hv00[l].y * w00 + hv10[l].y * w10 + hv01[l].y * w01 + hv11[l].y * w11;
    }

    float h0[16];
    #pragma unroll
    for (int j = 0; j < 16; ++j) {
        float aa = sb0[j];
        #pragma unroll
        for (int k = 0; k < 24; ++k) aa += enc[k] * sW0[k * 16 + j];
        h0[j] = __sinf(300.0f * aa);
    }
    float h1[16];
    #pragma unroll
    for (int j = 0; j < 16; ++j) {
        float aa = sb1[j];
        #pragma unroll
        for (int k = 0; k < 16; ++k) aa += h0[k] * sW1[k * 16 + j];
        h1[j] = __sinf(aa);
    }
    float h2[16];
    #pragma unroll
    for (int j = 0; j < 16; ++j) {
        float aa = sb2[j];
        #pragma unroll
        for (int k = 0; k < 16; ++k) aa += h1[k] * sW2[k * 16 + j];
        h2[j] = __sinf(aa);
    }
    float o = sb3;
    #pragma unroll
    for (int k = 0; k < 16; ++k) o += h2[k] * sW3[k];
    out[idx] = o;
}

extern "C" void kernel_launch(void* const* d_in, const int* in_sizes, int n_in,
                              void* d_out, int out_size, void* d_ws, size_t ws_size,
                              hipStream_t stream) {
    const float* coords = (const float*)d_in[0];
    const float* table  = (const float*)d_in[1];
    const float* W0 = (const float*)d_in[2];
    const float* b0 = (const float*)d_in[3];
    const float* W1 = (const float*)d_in[4];
    const float* b1 = (const float*)d_in[5];
    const float* W2 = (const float*)d_in[6];
    const float* b2 = (const float*)d_in[7];
    const float* W3 = (const float*)d_in[8];
    const float* b3 = (const float*)d_in[9];
    float* out = (float*)d_out;

    const int N = in_sizes[0] / 2;  // coords is [N,2]

    const size_t tab_w = (size_t)NHASH * TSIZE;          // u32 words
    const size_t enc_w = (size_t)NHASH * (size_t)N;      // u32 words (6 streams)
    const size_t need = tab_w * 4 + enc_w * 4 + 6144;    // + wfrag
    if (ws_size >= need) {
        unsigned* wtab = (unsigned*)d_ws;
        unsigned* wenc = wtab + tab_w;
        uint4v* wfrag = (uint4v*)(wenc + enc_w);
        convert_kernel<<<4096, 256, 0, stream>>>(table, wtab,
                                                 W0, b0, W1, b1, W2, b2, W3, wfrag);
        const int pgrid = (N + 1023) / 1024;
        for (int l = 0; l < NHASH; ++l)
            pass_kernel<<<pgrid, 256, 0, stream>>>(coords, wtab, wenc, l, N);
        mlp_kernel<<<(N + 255) / 256, 256, 0, stream>>>(coords, table, wenc, wfrag,
                                                        b3, out, N);
    } else {
        const int block = 256;
        const int grid = (N + block - 1) / block;
        hashsiren_fused<<<grid, block, 0, stream>>>(coords, table,
                                                    W0, b0, W1, b1, W2, b2, W3, b3,
                                                    out, N);
    }
}

// Round 11
// 175.232 us; speedup vs baseline: 1.0525x; 1.0248x over previous
//
#include <hip/hip_runtime.h>
#include <math.h>

#define TSIZE (1u << 20)
#define PRIME_Y 2654435761u
#define NHASH 6   // hashed levels 6..11

typedef __attribute__((ext_vector_type(8))) short short8;     // bf16x8 MFMA frag
typedef __attribute__((ext_vector_type(4))) float f32x4;      // MFMA acc frag
typedef __attribute__((ext_vector_type(4))) float float4v;
typedef __attribute__((ext_vector_type(2))) float float2v;
typedef __attribute__((ext_vector_type(4))) unsigned uint4v;
typedef __attribute__((ext_vector_type(2))) unsigned uint2v;

struct alignas(8) f4a8 { float x, y, z, w; };   // 16B row load at 8B alignment

__device__ __forceinline__ unsigned bf16rne(unsigned u) {
    return (u + 0x7fffu + ((u >> 16) & 1u)) >> 16;   // RNE to bf16 (in low 16)
}
__device__ __forceinline__ unsigned pack_bf16x2(float a, float b) {
    return (bf16rne(__float_as_uint(a)) & 0xffffu) | (bf16rne(__float_as_uint(b)) << 16);
}
__device__ __forceinline__ float2 unpack_bf16x2(unsigned u) {
    float2 r;
    r.x = __uint_as_float(u << 16);
    r.y = __uint_as_float(u & 0xffff0000u);
    return r;
}
__device__ __forceinline__ short f2bf(float x) {
    return (short)(bf16rne(__float_as_uint(x)) & 0xffffu);
}
__device__ __forceinline__ float bf2f(short h) {
    return __uint_as_float(((unsigned)(unsigned short)h) << 16);
}
// RTZ hi/lo split packed as {hi_bits | lo_bits<<16}; lo captures the full
// residual so total error ~2^-16 rel (cheaper than 2x RNE: 5 VALU ops).
__device__ __forceinline__ unsigned hilo_pack(float v) {
    const unsigned uv = __float_as_uint(v);
    const float l = v - __uint_as_float(uv & 0xffff0000u);
    return (uv >> 16) | (__float_as_uint(l) & 0xffff0000u);
}

// ---- pass 0: convert hashed tables f32->bf16x2 in ws; block 0 also builds
// the per-lane MFMA B-fragments.
__global__ __launch_bounds__(256) void convert_kernel(
    const float* __restrict__ table, unsigned* __restrict__ wtab,
    const float* __restrict__ W0, const float* __restrict__ b0,
    const float* __restrict__ W1, const float* __restrict__ b1,
    const float* __restrict__ W2, const float* __restrict__ b2,
    const float* __restrict__ W3,
    uint4v* __restrict__ wfrag)
{
    if (blockIdx.x == 0 && threadIdx.x < 64) {
        const int lane = threadIdx.x;
        const int n = lane & 15;
        const int kb = lane >> 4;
        short8 bf0, b1a, b1b, b2a, b2b;
        #pragma unroll
        for (int j = 0; j < 8; ++j) {
            const int k = kb * 8 + j;
            bf0[j] = (k < 24) ? f2bf(W0[k * 16 + n]) : (short)0;
            const int i = k >> 1;
            const float w1 = W1[i * 16 + n];
            const float w2 = W2[i * 16 + n];
            const short w1h = f2bf(w1), w2h = f2bf(w2);
            b1a[j] = w1h;
            b2a[j] = w2h;
            b1b[j] = (k & 1) ? (short)0 : f2bf(w1 - bf2f(w1h));
            b2b[j] = (k & 1) ? (short)0 : f2bf(w2 - bf2f(w2h));
        }
        union { short8 s; uint4v u; } cv;
        cv.s = bf0; wfrag[0 * 64 + lane] = cv.u;
        cv.s = b1a; wfrag[1 * 64 + lane] = cv.u;
        cv.s = b1b; wfrag[2 * 64 + lane] = cv.u;
        cv.s = b2a; wfrag[3 * 64 + lane] = cv.u;
        cv.s = b2b; wfrag[4 * 64 + lane] = cv.u;
        float4v bb;
        bb.x = b0[n]; bb.y = b1[n]; bb.z = b2[n]; bb.w = W3[n];
        union { float4v f; uint4v u; } cf; cf.f = bb;
        wfrag[5 * 64 + lane] = cf.u;
    }
    const size_t total4 = (size_t)NHASH * TSIZE / 2;   // float4 chunks (2 entries)
    const float4v* __restrict__ src =
        reinterpret_cast<const float4v*>(table + (size_t)6 * TSIZE * 2);
    uint2v* __restrict__ dst = reinterpret_cast<uint2v*>(wtab);
    for (size_t i = (size_t)blockIdx.x * 256 + threadIdx.x; i < total4;
         i += (size_t)gridDim.x * 256) {
        float4v v = __builtin_nontemporal_load(&src[i]);
        uint2v o;
        o.x = pack_bf16x2(v.x, v.y);
        o.y = pack_bf16x2(v.z, v.w);
        __builtin_nontemporal_store(o, &dst[i]);
    }
}

// ---- per-level hash pass: 4 consecutive points/thread, parity pair loads.
__global__ __launch_bounds__(256) void pass_kernel(const float* __restrict__ coords,
                                                   const unsigned* __restrict__ wtab,
                                                   unsigned* __restrict__ wenc,
                                                   int lvl, int N) {
    const int gid = blockIdx.x * 256 + threadIdx.x;
    const int base = gid * 4;
    if (base >= N) return;
    const int res = 16 << (lvl + 6);
    const unsigned* __restrict__ tl = wtab + (size_t)lvl * TSIZE;
    const uint2v* __restrict__ tl2 = reinterpret_cast<const uint2v*>(tl);
    unsigned* __restrict__ we = wenc + (size_t)lvl * N;

    if (base + 3 < N) {
        const float4v* __restrict__ c4 = reinterpret_cast<const float4v*>(coords);
        const float4v ca = __builtin_nontemporal_load(&c4[gid * 2]);
        const float4v cb = __builtin_nontemporal_load(&c4[gid * 2 + 1]);
        const float xs[4] = {ca.x, ca.z, cb.x, cb.z};
        const float ys[4] = {ca.y, ca.w, cb.y, cb.w};
        unsigned h00a[4], h01a[4], h10a[4], h11a[4], oddp[4];
        float wxs[4], wys[4];
        #pragma unroll
        for (int p = 0; p < 4; ++p) {
            const float px = xs[p] * (float)res;
            const float py = ys[p] * (float)res;
            const float fx = floorf(px), fy = floorf(py);
            wxs[p] = px - fx;
            wys[p] = py - fy;
            const unsigned ux = (unsigned)(int)fx, uy = (unsigned)(int)fy;
            const unsigned hy0 = uy * PRIME_Y;
            const unsigned hy1 = (uy + 1u) * PRIME_Y;
            h00a[p] = (ux ^ hy0) & (TSIZE - 1u);
            h01a[p] = (ux ^ hy1) & (TSIZE - 1u);
            h10a[p] = ((ux + 1u) ^ hy0) & (TSIZE - 1u);
            h11a[p] = ((ux + 1u) ^ hy1) & (TSIZE - 1u);
            oddp[p] = ux & 1u;
        }
        uint2v pr0[4], pr1[4];
        #pragma unroll
        for (int p = 0; p < 4; ++p) {
            pr0[p] = tl2[h00a[p] >> 1];
            pr1[p] = tl2[h01a[p] >> 1];
        }
        unsigned t10[4], t11[4];
        #pragma unroll
        for (int p = 0; p < 4; ++p) { t10[p] = 0u; t11[p] = 0u; }
        #pragma unroll
        for (int p = 0; p < 4; ++p) {
            if (oddp[p]) {
                t10[p] = tl[h10a[p]];
                t11[p] = tl[h11a[p]];
            }
        }
        uint4v r;
        #pragma unroll
        for (int p = 0; p < 4; ++p) {
            const unsigned s0 = h00a[p] & 1u;
            const unsigned s1 = h01a[p] & 1u;
            const unsigned v00 = s0 ? pr0[p].y : pr0[p].x;
            const unsigned v01 = s1 ? pr1[p].y : pr1[p].x;
            const unsigned v10 = oddp[p] ? t10[p] : (s0 ? pr0[p].x : pr0[p].y);
            const unsigned v11 = oddp[p] ? t11[p] : (s1 ? pr1[p].x : pr1[p].y);
            const float wx = wxs[p], wy = wys[p];
            const float w00 = (1.0f - wx) * (1.0f - wy);
            const float w10 = wx * (1.0f - wy);
            const float w01 = (1.0f - wx) * wy;
            const float w11 = wx * wy;
            const float2 f00 = unpack_bf16x2(v00);
            const float2 f10 = unpack_bf16x2(v10);
            const float2 f01 = unpack_bf16x2(v01);
            const float2 f11 = unpack_bf16x2(v11);
            const float e0 = f00.x * w00 + f10.x * w10 + f01.x * w01 + f11.x * w11;
            const float e1 = f00.y * w00 + f10.y * w10 + f01.y * w01 + f11.y * w11;
            r[p] = pack_bf16x2(e0, e1);
        }
        __builtin_nontemporal_store(r, &((uint4v*)we)[gid]);
    } else {
        for (int p = 0; p < 4 && base + p < N; ++p) {
            const float2 c = reinterpret_cast<const float2*>(coords)[base + p];
            const float px = c.x * (float)res;
            const float py = c.y * (float)res;
            const float fx = floorf(px), fy = floorf(py);
            const float wx = px - fx, wy = py - fy;
            const unsigned ux = (unsigned)(int)fx, uy = (unsigned)(int)fy;
            const unsigned hy0 = uy * PRIME_Y;
            const unsigned hy1 = (uy + 1u) * PRIME_Y;
            const float2 v00 = unpack_bf16x2(tl[(ux ^ hy0) & (TSIZE - 1u)]);
            const float2 v10 = unpack_bf16x2(tl[((ux + 1u) ^ hy0) & (TSIZE - 1u)]);
            const float2 v01 = unpack_bf16x2(tl[(ux ^ hy1) & (TSIZE - 1u)]);
            const float2 v11 = unpack_bf16x2(tl[((ux + 1u) ^ hy1) & (TSIZE - 1u)]);
            const float w00 = (1.0f - wx) * (1.0f - wy);
            const float w10 = wx * (1.0f - wy);
            const float w01 = (1.0f - wx) * wy;
            const float w11 = wx * wy;
            const float e0 = v00.x * w00 + v10.x * w10 + v01.x * w01 + v11.x * w11;
            const float e1 = v00.y * w00 + v10.y * w10 + v01.y * w01 + v11.y * w11;
            we[base + p] = pack_bf16x2(e0, e1);
        }
    }
}

// ---- stage one point's 12 packed enc words as an MFMA A-row (K 24->32)
__device__ __forceinline__ void stage_row(char* ldsw, int lane, const unsigned* u) {
    uint4v* rowp = (uint4v*)(ldsw + lane * 80);
    uint4v r0; r0.x = u[0]; r0.y = u[1]; r0.z = u[2]; r0.w = u[3];
    uint4v r1; r1.x = u[4]; r1.y = u[5]; r1.z = u[6]; r1.w = u[7];
    uint4v r2; r2.x = u[8]; r2.y = u[9]; r2.z = u[10]; r2.w = u[11];
    uint4v r3; r3.x = 0u; r3.y = 0u; r3.z = 0u; r3.w = 0u;  // keep: no NaN*0
    rowp[0] = r0; rowp[1] = r1; rowp[2] = r2; rowp[3] = r3;
}

// ---- final: dense levels + hashed enc streams + MFMA SIREN MLP.
// 2 points/thread = 2 independent MFMA tiles per wave (2x ILP on every phase).
// NO barriers: each tile's LDS region is wave-private; within-wave LDS
// ordering is handled by compiler-inserted lgkmcnt waits.
// Block covers 4 waves * 128 points = 512 points (grid = ceil(N/512)).
__global__ __launch_bounds__(256) void mlp_kernel(
    const float* __restrict__ coords,
    const float* __restrict__ table,
    const unsigned* __restrict__ wenc,
    const uint4v* __restrict__ wfrag,
    const float* __restrict__ b3p,
    float* __restrict__ out, int N)
{
    __shared__ char lds[40960];             // 4 waves * 2 tiles * 5120 B
    const int t = threadIdx.x;
    const int lane = t & 63;
    const int wv = t >> 6;
    const int n = lane & 15;
    const int kb = lane >> 4;
    char* lds0 = lds + wv * 10240;
    char* lds1 = lds0 + 5120;

    union { short8 s; uint4v u; } w0u, w1au, w1bu, w2au, w2bu;
    w0u.u  = wfrag[0 * 64 + lane];
    w1au.u = wfrag[1 * 64 + lane];
    w1bu.u = wfrag[2 * 64 + lane];
    w2au.u = wfrag[3 * 64 + lane];
    w2bu.u = wfrag[4 * 64 + lane];
    const short8 bf0 = w0u.s, b1a = w1au.s, b1b = w1bu.s, b2a = w2au.s, b2b = w2bu.s;
    union { float4v f; uint4v u; } cf;
    cf.u = wfrag[5 * 64 + lane];
    const float b0n = cf.f.x, b1n = cf.f.y, b2n = cf.f.z, w3n = cf.f.w;
    const float b3s = b3p[0];

    const int base = blockIdx.x * 512 + wv * 128;   // 4 waves * 128 pts = 512/block
    const int idx0 = base + lane;
    const int idx1 = idx0 + 64;
    const int i0 = (idx0 < N) ? idx0 : (N - 1);
    const int i1 = (idx1 < N) ? idx1 : (N - 1);

    // hashed enc words: already packed bf16x2 — go straight into the A-row
    unsigned u0[12], u1[12];
    #pragma unroll
    for (int l = 0; l < NHASH; ++l) {
        u0[6 + l] = __builtin_nontemporal_load(&wenc[(size_t)l * N + i0]);
        u1[6 + l] = __builtin_nontemporal_load(&wenc[(size_t)l * N + i1]);
    }
    const float2v cA = __builtin_nontemporal_load(
        reinterpret_cast<const float2v*>(coords) + i0);
    const float2v cB = __builtin_nontemporal_load(
        reinterpret_cast<const float2v*>(coords) + i1);

    #pragma unroll
    for (int lvl = 0; lvl < 6; ++lvl) {
        const int res = 16 << lvl;
        const int stride = res + 1;
        const float* __restrict__ tl = table + (size_t)lvl * TSIZE * 2u;
        {
            const float px = cA.x * (float)res;
            const float py = cA.y * (float)res;
            const float fx = floorf(px), fy = floorf(py);
            const float wx = px - fx, wy = py - fy;
            const int b = (int)fx + (int)fy * stride;
            const f4a8 r0 = *reinterpret_cast<const f4a8*>(tl + 2 * (size_t)b);
            const f4a8 r1 = *reinterpret_cast<const f4a8*>(tl + 2 * (size_t)(b + stride));
            const float w00 = (1.0f - wx) * (1.0f - wy);
            const float w10 = wx * (1.0f - wy);
            const float w01 = (1.0f - wx) * wy;
            const float w11 = wx * wy;
            u0[lvl] = pack_bf16x2(r0.x * w00 + r0.z * w10 + r1.x * w01 + r1.z * w11,
                                  r0.y * w00 + r0.w * w10 + r1.y * w01 + r1.w * w11);
        }
        {
            const float px = cB.x * (float)res;
            const float py = cB.y * (float)res;
            const float fx = floorf(px), fy = floorf(py);
            const float wx = px - fx, wy = py - fy;
            const int b = (int)fx + (int)fy * stride;
            const f4a8 r0 = *reinterpret_cast<const f4a8*>(tl + 2 * (size_t)b);
            const f4a8 r1 = *reinterpret_cast<const f4a8*>(tl + 2 * (size_t)(b + stride));
            const float w00 = (1.0f - wx) * (1.0f - wy);
            const float w10 = wx * (1.0f - wy);
            const float w01 = (1.0f - wx) * wy;
            const float w11 = wx * wy;
            u1[lvl] = pack_bf16x2(r0.x * w00 + r0.z * w10 + r1.x * w01 + r1.z * w11,
                                  r0.y * w00 + r0.w * w10 + r1.y * w01 + r1.w * w11);
        }
    }

    stage_row(lds0, lane, u0);
    stage_row(lds1, lane, u1);

    short8 a0[4], a1[4];
    #pragma unroll
    for (int m = 0; m < 4; ++m) {
        a0[m] = *(const short8*)(lds0 + (m * 16 + n) * 80 + kb * 16);
        a1[m] = *(const short8*)(lds1 + (m * 16 + n) * 80 + kb * 16);
    }

    const f32x4 z = {0.f, 0.f, 0.f, 0.f};
    f32x4 acc0[4], acc1[4];
    #pragma unroll
    for (int m = 0; m < 4; ++m) {
        acc0[m] = __builtin_amdgcn_mfma_f32_16x16x32_bf16(a0[m], bf0, z, 0, 0, 0);
        acc1[m] = __builtin_amdgcn_mfma_f32_16x16x32_bf16(a1[m], bf0, z, 0, 0, 0);
    }

    unsigned* hp0 = (unsigned*)lds0;   // rows of 20 words; word n = {hi|lo<<16}
    unsigned* hp1 = (unsigned*)lds1;

    // ---- layer 1: h = sin(300*(acc+b0)); RTZ hi/lo; mfma hi+lo
    #pragma unroll
    for (int m = 0; m < 4; ++m) {
        #pragma unroll
        for (int r = 0; r < 4; ++r) {
            const int row = m * 16 + kb * 4 + r;
            hp0[row * 20 + n] = hilo_pack(__sinf(300.0f * (acc0[m][r] + b0n)));
            hp1[row * 20 + n] = hilo_pack(__sinf(300.0f * (acc1[m][r] + b0n)));
        }
    }
    #pragma unroll
    for (int m = 0; m < 4; ++m) {
        a0[m] = *(const short8*)(lds0 + (m * 16 + n) * 80 + kb * 16);
        a1[m] = *(const short8*)(lds1 + (m * 16 + n) * 80 + kb * 16);
    }
    #pragma unroll
    for (int m = 0; m < 4; ++m) {
        f32x4 p0 = __builtin_amdgcn_mfma_f32_16x16x32_bf16(a0[m], b1a, z, 0, 0, 0);
        acc0[m] = __builtin_amdgcn_mfma_f32_16x16x32_bf16(a0[m], b1b, p0, 0, 0, 0);
        f32x4 p1 = __builtin_amdgcn_mfma_f32_16x16x32_bf16(a1[m], b1a, z, 0, 0, 0);
        acc1[m] = __builtin_amdgcn_mfma_f32_16x16x32_bf16(a1[m], b1b, p1, 0, 0, 0);
    }

    // ---- layer 2
    #pragma unroll
    for (int m = 0; m < 4; ++m) {
        #pragma unroll
        for (int r = 0; r < 4; ++r) {
            const int row = m * 16 + kb * 4 + r;
            hp0[row * 20 + n] = hilo_pack(__sinf(acc0[m][r] + b1n));
            hp1[row * 20 + n] = hilo_pack(__sinf(acc1[m][r] + b1n));
        }
    }
    #pragma unroll
    for (int m = 0; m < 4; ++m) {
        a0[m] = *(const short8*)(lds0 + (m * 16 + n) * 80 + kb * 16);
        a1[m] = *(const short8*)(lds1 + (m * 16 + n) * 80 + kb * 16);
    }
    #pragma unroll
    for (int m = 0; m < 4; ++m) {
        f32x4 p0 = __builtin_amdgcn_mfma_f32_16x16x32_bf16(a0[m], b2a, z, 0, 0, 0);
        acc0[m] = __builtin_amdgcn_mfma_f32_16x16x32_bf16(a0[m], b2b, p0, 0, 0, 0);
        f32x4 p1 = __builtin_amdgcn_mfma_f32_16x16x32_bf16(a1[m], b2a, z, 0, 0, 0);
        acc1[m] = __builtin_amdgcn_mfma_f32_16x16x32_bf16(a1[m], b2b, p1, 0, 0, 0);
    }

    // ---- layer 3 (16->1) in f32: shuffle-reduce over the 16 n-lanes
    const int m2 = n >> 2, r2 = n & 3;
    float ov0 = 0.f, ov1 = 0.f;
    #pragma unroll
    for (int m = 0; m < 4; ++m) {
        #pragma unroll
        for (int r = 0; r < 4; ++r) {
            float v0 = __sinf(acc0[m][r] + b2n) * w3n;
            float v1 = __sinf(acc1[m][r] + b2n) * w3n;
            v0 += __shfl_xor(v0, 1);  v1 += __shfl_xor(v1, 1);
            v0 += __shfl_xor(v0, 2);  v1 += __shfl_xor(v1, 2);
            v0 += __shfl_xor(v0, 4);  v1 += __shfl_xor(v1, 4);
            v0 += __shfl_xor(v0, 8);  v1 += __shfl_xor(v1, 8);
            if (m == m2 && r == r2) { ov0 = v0; ov1 = v1; }
        }
    }
    const int g0 = base + m2 * 16 + kb * 4 + r2;
    const int g1 = g0 + 64;
    if (g0 < N) __builtin_nontemporal_store(ov0 + b3s, &out[g0]);
    if (g1 < N) __builtin_nontemporal_store(ov1 + b3s, &out[g1]);
}

// ---- fallback: R1 fused kernel (known-good) for small ws
__global__ __launch_bounds__(256) void hashsiren_fused(
    const float* __restrict__ coords,
    const float* __restrict__ table,
    const float* __restrict__ W0, const float* __restrict__ b0,
    const float* __restrict__ W1, const float* __restrict__ b1,
    const float* __restrict__ W2, const float* __restrict__ b2,
    const float* __restrict__ W3, const float* __restrict__ b3,
    float* __restrict__ out, int N)
{
    __shared__ float sW0[384];
    __shared__ float sW1[256];
    __shared__ float sW2[256];
    __shared__ float sb0[16], sb1[16], sb2[16], sW3[16];
    __shared__ float sb3;

    const int t = threadIdx.x;
    for (int i = t; i < 384; i += 256) sW0[i] = W0[i];
    sW1[t] = W1[t];
    sW2[t] = W2[t];
    if (t < 16) { sb0[t] = b0[t]; sb1[t] = b1[t]; sb2[t] = b2[t]; sW3[t] = W3[t]; }
    if (t == 0) sb3 = b3[0];
    __syncthreads();

    const int idx = blockIdx.x * 256 + t;
    if (idx >= N) return;

    const float2 c = reinterpret_cast<const float2*>(coords)[idx];

    float2 hv00[6], hv10[6], hv01[6], hv11[6];
    float hwx[6], hwy[6];
    #pragma unroll
    for (int l = 0; l < 6; ++l) {
        const int res = 16 << (l + 6);
        const float px = c.x * (float)res;
        const float py = c.y * (float)res;
        const float fx = floorf(px), fy = floorf(py);
        hwx[l] = px - fx;
        hwy[l] = py - fy;
        const unsigned ux = (unsigned)(int)fx, uy = (unsigned)(int)fy;
        const unsigned hy0 = uy * PRIME_Y;
        const unsigned hy1 = (uy + 1u) * PRIME_Y;
        const float2* __restrict__ tl =
            reinterpret_cast<const float2*>(table) + (size_t)(l + 6) * TSIZE;
        hv00[l] = tl[(ux ^ hy0) & (TSIZE - 1u)];
        hv10[l] = tl[((ux + 1u) ^ hy0) & (TSIZE - 1u)];
        hv01[l] = tl[(ux ^ hy1) & (TSIZE - 1u)];
        hv11[l] = tl[((ux + 1u) ^ hy1) & (TSIZE - 1u)];
    }

    float enc[24];
    #pragma unroll
    for (int lvl = 0; lvl < 6; ++lvl) {
        const int res = 16 << lvl;
        const float px = c.x * (float)res;
        const float py = c.y * (float)res;
        const float fx = floorf(px), fy = floorf(py);
        const float wx = px - fx, wy = py - fy;
        const int ix = (int)fx, iy = (int)fy;
        const int stride = res + 1;
        const int base = ix + iy * stride;
        const float2* __restrict__ tl =
            reinterpret_cast<const float2*>(table) + (size_t)lvl * TSIZE;
        const float2 v00 = tl[base];
        const float2 v10 = tl[base + 1];
        const float2 v01 = tl[base + stride];
        const float2 v11 = tl[base + stride + 1];
        const float w00 = (1.0f - wx) * (1.0f - wy);
        const float w10 = wx * (1.0f - wy);
        const float w01 = (1.0f - wx) * wy;
        const float w11 = wx * wy;
        enc[2 * lvl]     = v00.x * w00 + v10.x * w10 + v01.x * w01 + v11.x * w11;
        enc[2 * lvl + 1] = v00.y * w00 + v10.y * w10 + v01.y * w01 + v11.y * w11;
    }
    #pragma unroll
    for (int l = 0; l < 6; ++l) {
        const float wx = hwx[l], wy = hwy[l];
        const float w00 = (1.0f - wx) * (1.0f - wy);
        const float w10 = wx * (1.0f - wy);
        const float w01 = (1.0f - wx) * wy;
        const float w11 = wx * wy;
        enc[2 * (l + 6)]     = hv00[l].x * w00 + hv10[l].x * w10 + hv01[l].x * w01 + hv11[l].x * w11;
        enc[2 * (l + 6) + 1] = hv00[l].y * w00 + hv10[l].y * w10 + hv01[l].y * w01 + hv11[l].y * w11;
    }

    float h0[16];
    #pragma unroll
    for (int j = 0; j < 16; ++j) {
        float aa = sb0[j];
        #pragma unroll
        for (int k = 0; k < 24; ++k) aa += enc[k] * sW0[k * 16 + j];
        h0[j] = __sinf(300.0f * aa);
    }
    float h1[16];
    #pragma unroll
    for (int j = 0; j < 16; ++j) {
        float aa = sb1[j];
        #pragma unroll
        for (int k = 0; k < 16; ++k) aa += h0[k] * sW1[k * 16 + j];
        h1[j] = __sinf(aa);
    }
    float h2[16];
    #pragma unroll
    for (int j = 0; j < 16; ++j) {
        float aa = sb2[j];
        #pragma unroll
        for (int k = 0; k < 16; ++k) aa += h1[k] * sW2[k * 16 + j];
        h2[j] = __sinf(aa);
    }
    float o = sb3;
    #pragma unroll
    for (int k = 0; k < 16; ++k) o += h2[k] * sW3[k];
    out[idx] = o;
}

extern "C" void kernel_launch(void* const* d_in, const int* in_sizes, int n_in,
                              void* d_out, int out_size, void* d_ws, size_t ws_size,
                              hipStream_t stream) {
    const float* coords = (const float*)d_in[0];
    const float* table  = (const float*)d_in[1];
    const float* W0 = (const float*)d_in[2];
    const float* b0 = (const float*)d_in[3];
    const float* W1 = (const float*)d_in[4];
    const float* b1 = (const float*)d_in[5];
    const float* W2 = (const float*)d_in[6];
    const float* b2 = (const float*)d_in[7];
    const float* W3 = (const float*)d_in[8];
    const float* b3 = (const float*)d_in[9];
    float* out = (float*)d_out;

    const int N = in_sizes[0] / 2;  // coords is [N,2]

    const size_t tab_w = (size_t)NHASH * TSIZE;          // u32 words
    const size_t enc_w = (size_t)NHASH * (size_t)N;      // u32 words (6 streams)
    const size_t need = tab_w * 4 + enc_w * 4 + 6144;    // + wfrag
    if (ws_size >= need) {
        unsigned* wtab = (unsigned*)d_ws;
        unsigned* wenc = wtab + tab_w;
        uint4v* wfrag = (uint4v*)(wenc + enc_w);
        convert_kernel<<<4096, 256, 0, stream>>>(table, wtab,
                                                 W0, b0, W1, b1, W2, b2, W3, wfrag);
        const int pgrid = (N + 1023) / 1024;
        for (int l = 0; l < NHASH; ++l)
            pass_kernel<<<pgrid, 256, 0, stream>>>(coords, wtab, wenc, l, N);
        mlp_kernel<<<(N + 511) / 512, 256, 0, stream>>>(coords, table, wenc, wfrag,
                                                        b3, out, N);
    } else {
        const int block = 256;
        const int grid = (N + block - 1) / block;
        hashsiren_fused<<<grid, block, 0, stream>>>(coords, table,
                                                    W0, b0, W1, b1, W2, b2, W3, b3,
                                                    out, N);
    }
}

// Round 12
// 162.690 us; speedup vs baseline: 1.1336x; 1.0771x over previous
//
#include <hip/hip_runtime.h>
#include <math.h>

#define TSIZE (1u << 20)
#define PRIME_Y 2654435761u
#define NHASH 6   // hashed levels 6..11

typedef __attribute__((ext_vector_type(8))) short short8;     // bf16x8 MFMA frag
typedef __attribute__((ext_vector_type(4))) float f32x4;      // MFMA acc frag
typedef __attribute__((ext_vector_type(4))) float float4v;
typedef __attribute__((ext_vector_type(2))) float float2v;
typedef __attribute__((ext_vector_type(4))) unsigned uint4v;
typedef __attribute__((ext_vector_type(2))) unsigned uint2v;

struct alignas(8) f4a8 { float x, y, z, w; };   // 16B row load at 8B alignment

__device__ __forceinline__ unsigned bf16rne(unsigned u) {
    return (u + 0x7fffu + ((u >> 16) & 1u)) >> 16;   // RNE to bf16 (in low 16)
}
__device__ __forceinline__ unsigned pack_bf16x2(float a, float b) {
    return (bf16rne(__float_as_uint(a)) & 0xffffu) | (bf16rne(__float_as_uint(b)) << 16);
}
__device__ __forceinline__ float2 unpack_bf16x2(unsigned u) {
    float2 r;
    r.x = __uint_as_float(u << 16);
    r.y = __uint_as_float(u & 0xffff0000u);
    return r;
}
__device__ __forceinline__ short f2bf(float x) {
    return (short)(bf16rne(__float_as_uint(x)) & 0xffffu);
}
__device__ __forceinline__ float bf2f(short h) {
    return __uint_as_float(((unsigned)(unsigned short)h) << 16);
}
// RTZ hi/lo split packed as {hi_bits | lo_bits<<16}
__device__ __forceinline__ unsigned hilo_pack(float v) {
    const unsigned uv = __float_as_uint(v);
    const float l = v - __uint_as_float(uv & 0xffff0000u);
    return (uv >> 16) | (__float_as_uint(l) & 0xffff0000u);
}

// ---- fp8 e4m3 with x2^13 pre-scale (table values +-1e-4 -> ~0.8, all normal).
// encode: RNE to 3-bit mantissa, FTZ on underflow (err <= ~2e-6 pre-scale).
__device__ __forceinline__ unsigned fp8e(float f) {
    const float v = f * 8192.0f;
    const unsigned a = __float_as_uint(v);
    const unsigned sign = (a >> 31) << 7;
    const unsigned mag = a & 0x7fffffffu;
    const unsigned r = mag + 0x7ffffu + ((mag >> 20) & 1u);
    int u = (int)(r >> 20) - (120 << 3);
    u = (u < 0) ? 0 : u;
    return (unsigned)u | sign;
}
// decode with 2^-13 descale folded into the exponent rebias (e+127-7-13=e+107).
// u8==0 decodes to ~9.5e-7 instead of 0 — below e4m3 quantization error.
__device__ __forceinline__ float fp8d(unsigned u8) {
    const unsigned bits = ((u8 & 0x80u) << 24) |
                          (((u8 & 0x7fu) << 20) + (107u << 23));
    return __uint_as_float(bits);
}
__device__ __forceinline__ float2 fp8d2(unsigned u16) {   // {x:lo8, y:hi8}
    float2 r;
    r.x = fp8d(u16 & 0xffu);
    r.y = fp8d((u16 >> 8) & 0xffu);
    return r;
}

// ---- pass 0: convert hashed tables f32 -> fp8-pair (2 MiB/level, L2-resident);
// block 0 also builds the per-lane MFMA B-fragments. NORMAL stores: table must
// land in cache hierarchy, not bypass it.
__global__ __launch_bounds__(256) void convert_kernel(
    const float* __restrict__ table, unsigned* __restrict__ wtab8,
    const float* __restrict__ W0, const float* __restrict__ b0,
    const float* __restrict__ W1, const float* __restrict__ b1,
    const float* __restrict__ W2, const float* __restrict__ b2,
    const float* __restrict__ W3,
    uint4v* __restrict__ wfrag)
{
    if (blockIdx.x == 0 && threadIdx.x < 64) {
        const int lane = threadIdx.x;
        const int n = lane & 15;
        const int kb = lane >> 4;
        short8 bf0, b1a, b1b, b2a, b2b;
        #pragma unroll
        for (int j = 0; j < 8; ++j) {
            const int k = kb * 8 + j;
            bf0[j] = (k < 24) ? f2bf(W0[k * 16 + n]) : (short)0;
            const int i = k >> 1;
            const float w1 = W1[i * 16 + n];
            const float w2 = W2[i * 16 + n];
            const short w1h = f2bf(w1), w2h = f2bf(w2);
            b1a[j] = w1h;
            b2a[j] = w2h;
            b1b[j] = (k & 1) ? (short)0 : f2bf(w1 - bf2f(w1h));
            b2b[j] = (k & 1) ? (short)0 : f2bf(w2 - bf2f(w2h));
        }
        union { short8 s; uint4v u; } cv;
        cv.s = bf0; wfrag[0 * 64 + lane] = cv.u;
        cv.s = b1a; wfrag[1 * 64 + lane] = cv.u;
        cv.s = b1b; wfrag[2 * 64 + lane] = cv.u;
        cv.s = b2a; wfrag[3 * 64 + lane] = cv.u;
        cv.s = b2b; wfrag[4 * 64 + lane] = cv.u;
        float4v bb;
        bb.x = b0[n]; bb.y = b1[n]; bb.z = b2[n]; bb.w = W3[n];
        union { float4v f; uint4v u; } cf; cf.f = bb;
        wfrag[5 * 64 + lane] = cf.u;
    }
    const size_t total4 = (size_t)NHASH * TSIZE / 2;   // float4 chunks (2 entries)
    const float4v* __restrict__ src =
        reinterpret_cast<const float4v*>(table + (size_t)6 * TSIZE * 2);
    for (size_t i = (size_t)blockIdx.x * 256 + threadIdx.x; i < total4;
         i += (size_t)gridDim.x * 256) {
        float4v v = __builtin_nontemporal_load(&src[i]);
        wtab8[i] = fp8e(v.x) | (fp8e(v.y) << 8) | (fp8e(v.z) << 16) | (fp8e(v.w) << 24);
    }
}

// ---- per-level hash pass: 4 points/thread. fp8 entries: a corner-PAIR
// (h, h^1) is ONE aligned u32. Odd-ux corners: exec-masked 2B loads.
// 2 MiB table + ~1.5 MB/XCD streams < 4 MiB L2 -> gathers hit local L2.
__global__ __launch_bounds__(256) void pass_kernel(const float* __restrict__ coords,
                                                   const unsigned* __restrict__ wtab8,
                                                   unsigned* __restrict__ wenc,
                                                   int lvl, int N) {
    const int gid = blockIdx.x * 256 + threadIdx.x;
    const int base = gid * 4;
    if (base >= N) return;
    const int res = 16 << (lvl + 6);
    const unsigned* __restrict__ tlp = wtab8 + ((size_t)lvl * TSIZE >> 1);  // u32 pairs
    const unsigned short* __restrict__ tl8 =
        reinterpret_cast<const unsigned short*>(tlp);
    unsigned* __restrict__ we = wenc + (size_t)lvl * N;

    if (base + 3 < N) {
        const float4v* __restrict__ c4 = reinterpret_cast<const float4v*>(coords);
        const float4v ca = __builtin_nontemporal_load(&c4[gid * 2]);
        const float4v cb = __builtin_nontemporal_load(&c4[gid * 2 + 1]);
        const float xs[4] = {ca.x, ca.z, cb.x, cb.z};
        const float ys[4] = {ca.y, ca.w, cb.y, cb.w};
        unsigned h00a[4], h01a[4], h10a[4], h11a[4], oddp[4];
        float wxs[4], wys[4];
        #pragma unroll
        for (int p = 0; p < 4; ++p) {
            const float px = xs[p] * (float)res;
            const float py = ys[p] * (float)res;
            const float fx = floorf(px), fy = floorf(py);
            wxs[p] = px - fx;
            wys[p] = py - fy;
            const unsigned ux = (unsigned)(int)fx, uy = (unsigned)(int)fy;
            const unsigned hy0 = uy * PRIME_Y;
            const unsigned hy1 = (uy + 1u) * PRIME_Y;
            h00a[p] = (ux ^ hy0) & (TSIZE - 1u);
            h01a[p] = (ux ^ hy1) & (TSIZE - 1u);
            h10a[p] = ((ux + 1u) ^ hy0) & (TSIZE - 1u);
            h11a[p] = ((ux + 1u) ^ hy1) & (TSIZE - 1u);
            oddp[p] = ux & 1u;
        }
        unsigned pr0[4], pr1[4];
        #pragma unroll
        for (int p = 0; p < 4; ++p) {
            pr0[p] = tlp[h00a[p] >> 1];
            pr1[p] = tlp[h01a[p] >> 1];
        }
        unsigned t10[4], t11[4];
        #pragma unroll
        for (int p = 0; p < 4; ++p) { t10[p] = 0u; t11[p] = 0u; }
        #pragma unroll
        for (int p = 0; p < 4; ++p) {
            if (oddp[p]) {
                t10[p] = tl8[h10a[p]];
                t11[p] = tl8[h11a[p]];
            }
        }
        uint4v r;
        #pragma unroll
        for (int p = 0; p < 4; ++p) {
            const unsigned s0 = h00a[p] & 1u;
            const unsigned s1 = h01a[p] & 1u;
            const unsigned e00 = s0 ? (pr0[p] >> 16) : (pr0[p] & 0xffffu);
            const unsigned e01 = s1 ? (pr1[p] >> 16) : (pr1[p] & 0xffffu);
            const unsigned e10 = oddp[p] ? t10[p]
                                         : (s0 ? (pr0[p] & 0xffffu) : (pr0[p] >> 16));
            const unsigned e11 = oddp[p] ? t11[p]
                                         : (s1 ? (pr1[p] & 0xffffu) : (pr1[p] >> 16));
            const float wx = wxs[p], wy = wys[p];
            const float w00 = (1.0f - wx) * (1.0f - wy);
            const float w10 = wx * (1.0f - wy);
            const float w01 = (1.0f - wx) * wy;
            const float w11 = wx * wy;
            const float2 f00 = fp8d2(e00);
            const float2 f10 = fp8d2(e10);
            const float2 f01 = fp8d2(e01);
            const float2 f11 = fp8d2(e11);
            const float e0 = f00.x * w00 + f10.x * w10 + f01.x * w01 + f11.x * w11;
            const float e1 = f00.y * w00 + f10.y * w10 + f01.y * w01 + f11.y * w11;
            r[p] = pack_bf16x2(e0, e1);
        }
        ((uint4v*)we)[gid] = r;   // normal store: enc stays in L2/L3 for mlp
    } else {
        for (int p = 0; p < 4 && base + p < N; ++p) {
            const float2 c = reinterpret_cast<const float2*>(coords)[base + p];
            const float px = c.x * (float)res;
            const float py = c.y * (float)res;
            const float fx = floorf(px), fy = floorf(py);
            const float wx = px - fx, wy = py - fy;
            const unsigned ux = (unsigned)(int)fx, uy = (unsigned)(int)fy;
            const unsigned hy0 = uy * PRIME_Y;
            const unsigned hy1 = (uy + 1u) * PRIME_Y;
            const float2 v00 = fp8d2(tl8[(ux ^ hy0) & (TSIZE - 1u)]);
            const float2 v10 = fp8d2(tl8[((ux + 1u) ^ hy0) & (TSIZE - 1u)]);
            const float2 v01 = fp8d2(tl8[(ux ^ hy1) & (TSIZE - 1u)]);
            const float2 v11 = fp8d2(tl8[((ux + 1u) ^ hy1) & (TSIZE - 1u)]);
            const float w00 = (1.0f - wx) * (1.0f - wy);
            const float w10 = wx * (1.0f - wy);
            const float w01 = (1.0f - wx) * wy;
            const float w11 = wx * wy;
            const float e0 = v00.x * w00 + v10.x * w10 + v01.x * w01 + v11.x * w11;
            const float e1 = v00.y * w00 + v10.y * w10 + v01.y * w01 + v11.y * w11;
            we[base + p] = pack_bf16x2(e0, e1);
        }
    }
}

// ---- stage one point's 12 packed enc words as an MFMA A-row (K 24->32)
__device__ __forceinline__ void stage_row(char* ldsw, int lane, const unsigned* u) {
    uint4v* rowp = (uint4v*)(ldsw + lane * 80);
    uint4v r0; r0.x = u[0]; r0.y = u[1]; r0.z = u[2]; r0.w = u[3];
    uint4v r1; r1.x = u[4]; r1.y = u[5]; r1.z = u[6]; r1.w = u[7];
    uint4v r2; r2.x = u[8]; r2.y = u[9]; r2.z = u[10]; r2.w = u[11];
    uint4v r3; r3.x = 0u; r3.y = 0u; r3.z = 0u; r3.w = 0u;  // keep: no NaN*0
    rowp[0] = r0; rowp[1] = r1; rowp[2] = r2; rowp[3] = r3;
}

// ---- final: dense levels + hashed enc streams + MFMA SIREN MLP.
// 2 points/thread, no barriers (wave-private LDS regions).
// Block covers 4 waves * 128 points = 512 points (grid = ceil(N/512)).
__global__ __launch_bounds__(256) void mlp_kernel(
    const float* __restrict__ coords,
    const float* __restrict__ table,
    const unsigned* __restrict__ wenc,
    const uint4v* __restrict__ wfrag,
    const float* __restrict__ b3p,
    float* __restrict__ out, int N)
{
    __shared__ char lds[40960];             // 4 waves * 2 tiles * 5120 B
    const int t = threadIdx.x;
    const int lane = t & 63;
    const int wv = t >> 6;
    const int n = lane & 15;
    const int kb = lane >> 4;
    char* lds0 = lds + wv * 10240;
    char* lds1 = lds0 + 5120;

    union { short8 s; uint4v u; } w0u, w1au, w1bu, w2au, w2bu;
    w0u.u  = wfrag[0 * 64 + lane];
    w1au.u = wfrag[1 * 64 + lane];
    w1bu.u = wfrag[2 * 64 + lane];
    w2au.u = wfrag[3 * 64 + lane];
    w2bu.u = wfrag[4 * 64 + lane];
    const short8 bf0 = w0u.s, b1a = w1au.s, b1b = w1bu.s, b2a = w2au.s, b2b = w2bu.s;
    union { float4v f; uint4v u; } cf;
    cf.u = wfrag[5 * 64 + lane];
    const float b0n = cf.f.x, b1n = cf.f.y, b2n = cf.f.z, w3n = cf.f.w;
    const float b3s = b3p[0];

    const int base = blockIdx.x * 512 + wv * 128;   // 4 waves * 128 pts
    const int idx0 = base + lane;
    const int idx1 = idx0 + 64;
    const int i0 = (idx0 < N) ? idx0 : (N - 1);
    const int i1 = (idx1 < N) ? idx1 : (N - 1);

    // hashed enc words (normal loads: written normally by passes -> cache hit)
    unsigned u0[12], u1[12];
    #pragma unroll
    for (int l = 0; l < NHASH; ++l) {
        u0[6 + l] = wenc[(size_t)l * N + i0];
        u1[6 + l] = wenc[(size_t)l * N + i1];
    }
    const float2v cA = reinterpret_cast<const float2v*>(coords)[i0];
    const float2v cB = reinterpret_cast<const float2v*>(coords)[i1];

    #pragma unroll
    for (int lvl = 0; lvl < 6; ++lvl) {
        const int res = 16 << lvl;
        const int stride = res + 1;
        const float* __restrict__ tl = table + (size_t)lvl * TSIZE * 2u;
        {
            const float px = cA.x * (float)res;
            const float py = cA.y * (float)res;
            const float fx = floorf(px), fy = floorf(py);
            const float wx = px - fx, wy = py - fy;
            const int b = (int)fx + (int)fy * stride;
            const f4a8 r0 = *reinterpret_cast<const f4a8*>(tl + 2 * (size_t)b);
            const f4a8 r1 = *reinterpret_cast<const f4a8*>(tl + 2 * (size_t)(b + stride));
            const float w00 = (1.0f - wx) * (1.0f - wy);
            const float w10 = wx * (1.0f - wy);
            const float w01 = (1.0f - wx) * wy;
            const float w11 = wx * wy;
            u0[lvl] = pack_bf16x2(r0.x * w00 + r0.z * w10 + r1.x * w01 + r1.z * w11,
                                  r0.y * w00 + r0.w * w10 + r1.y * w01 + r1.w * w11);
        }
        {
            const float px = cB.x * (float)res;
            const float py = cB.y * (float)res;
            const float fx = floorf(px), fy = floorf(py);
            const float wx = px - fx, wy = py - fy;
            const int b = (int)fx + (int)fy * stride;
            const f4a8 r0 = *reinterpret_cast<const f4a8*>(tl + 2 * (size_t)b);
            const f4a8 r1 = *reinterpret_cast<const f4a8*>(tl + 2 * (size_t)(b + stride));
            const float w00 = (1.0f - wx) * (1.0f - wy);
            const float w10 = wx * (1.0f - wy);
            const float w01 = (1.0f - wx) * wy;
            const float w11 = wx * wy;
            u1[lvl] = pack_bf16x2(r0.x * w00 + r0.z * w10 + r1.x * w01 + r1.z * w11,
                                  r0.y * w00 + r0.w * w10 + r1.y * w01 + r1.w * w11);
        }
    }

    stage_row(lds0, lane, u0);
    stage_row(lds1, lane, u1);

    short8 a0[4], a1[4];
    #pragma unroll
    for (int m = 0; m < 4; ++m) {
        a0[m] = *(const short8*)(lds0 + (m * 16 + n) * 80 + kb * 16);
        a1[m] = *(const short8*)(lds1 + (m * 16 + n) * 80 + kb * 16);
    }

    const f32x4 z = {0.f, 0.f, 0.f, 0.f};
    f32x4 acc0[4], acc1[4];
    #pragma unroll
    for (int m = 0; m < 4; ++m) {
        acc0[m] = __builtin_amdgcn_mfma_f32_16x16x32_bf16(a0[m], bf0, z, 0, 0, 0);
        acc1[m] = __builtin_amdgcn_mfma_f32_16x16x32_bf16(a1[m], bf0, z, 0, 0, 0);
    }

    unsigned* hp0 = (unsigned*)lds0;   // rows of 20 words; word n = {hi|lo<<16}
    unsigned* hp1 = (unsigned*)lds1;

    // ---- layer 1
    #pragma unroll
    for (int m = 0; m < 4; ++m) {
        #pragma unroll
        for (int r = 0; r < 4; ++r) {
            const int row = m * 16 + kb * 4 + r;
            hp0[row * 20 + n] = hilo_pack(__sinf(300.0f * (acc0[m][r] + b0n)));
            hp1[row * 20 + n] = hilo_pack(__sinf(300.0f * (acc1[m][r] + b0n)));
        }
    }
    #pragma unroll
    for (int m = 0; m < 4; ++m) {
        a0[m] = *(const short8*)(lds0 + (m * 16 + n) * 80 + kb * 16);
        a1[m] = *(const short8*)(lds1 + (m * 16 + n) * 80 + kb * 16);
    }
    #pragma unroll
    for (int m = 0; m < 4; ++m) {
        f32x4 p0 = __builtin_amdgcn_mfma_f32_16x16x32_bf16(a0[m], b1a, z, 0, 0, 0);
        acc0[m] = __builtin_amdgcn_mfma_f32_16x16x32_bf16(a0[m], b1b, p0, 0, 0, 0);
        f32x4 p1 = __builtin_amdgcn_mfma_f32_16x16x32_bf16(a1[m], b1a, z, 0, 0, 0);
        acc1[m] = __builtin_amdgcn_mfma_f32_16x16x32_bf16(a1[m], b1b, p1, 0, 0, 0);
    }

    // ---- layer 2
    #pragma unroll
    for (int m = 0; m < 4; ++m) {
        #pragma unroll
        for (int r = 0; r < 4; ++r) {
            const int row = m * 16 + kb * 4 + r;
            hp0[row * 20 + n] = hilo_pack(__sinf(acc0[m][r] + b1n));
            hp1[row * 20 + n] = hilo_pack(__sinf(acc1[m][r] + b1n));
        }
    }
    #pragma unroll
    for (int m = 0; m < 4; ++m) {
        a0[m] = *(const short8*)(lds0 + (m * 16 + n) * 80 + kb * 16);
        a1[m] = *(const short8*)(lds1 + (m * 16 + n) * 80 + kb * 16);
    }
    #pragma unroll
    for (int m = 0; m < 4; ++m) {
        f32x4 p0 = __builtin_amdgcn_mfma_f32_16x16x32_bf16(a0[m], b2a, z, 0, 0, 0);
        acc0[m] = __builtin_amdgcn_mfma_f32_16x16x32_bf16(a0[m], b2b, p0, 0, 0, 0);
        f32x4 p1 = __builtin_amdgcn_mfma_f32_16x16x32_bf16(a1[m], b2a, z, 0, 0, 0);
        acc1[m] = __builtin_amdgcn_mfma_f32_16x16x32_bf16(a1[m], b2b, p1, 0, 0, 0);
    }

    // ---- layer 3 (16->1) in f32: shuffle-reduce over the 16 n-lanes
    const int m2 = n >> 2, r2 = n & 3;
    float ov0 = 0.f, ov1 = 0.f;
    #pragma unroll
    for (int m = 0; m < 4; ++m) {
        #pragma unroll
        for (int r = 0; r < 4; ++r) {
            float v0 = __sinf(acc0[m][r] + b2n) * w3n;
            float v1 = __sinf(acc1[m][r] + b2n) * w3n;
            v0 += __shfl_xor(v0, 1);  v1 += __shfl_xor(v1, 1);
            v0 += __shfl_xor(v0, 2);  v1 += __shfl_xor(v1, 2);
            v0 += __shfl_xor(v0, 4);  v1 += __shfl_xor(v1, 4);
            v0 += __shfl_xor(v0, 8);  v1 += __shfl_xor(v1, 8);
            if (m == m2 && r == r2) { ov0 = v0; ov1 = v1; }
        }
    }
    const int g0 = base + m2 * 16 + kb * 4 + r2;
    const int g1 = g0 + 64;
    if (g0 < N) __builtin_nontemporal_store(ov0 + b3s, &out[g0]);
    if (g1 < N) __builtin_nontemporal_store(ov1 + b3s, &out[g1]);
}

// ---- fallback: R1 fused kernel (known-good) for small ws
__global__ __launch_bounds__(256) void hashsiren_fused(
    const float* __restrict__ coords,
    const float* __restrict__ table,
    const float* __restrict__ W0, const float* __restrict__ b0,
    const float* __restrict__ W1, const float* __restrict__ b1,
    const float* __restrict__ W2, const float* __restrict__ b2,
    const float* __restrict__ W3, const float* __restrict__ b3,
    float* __restrict__ out, int N)
{
    __shared__ float sW0[384];
    __shared__ float sW1[256];
    __shared__ float sW2[256];
    __shared__ float sb0[16], sb1[16], sb2[16], sW3[16];
    __shared__ float sb3;

    const int t = threadIdx.x;
    for (int i = t; i < 384; i += 256) sW0[i] = W0[i];
    sW1[t] = W1[t];
    sW2[t] = W2[t];
    if (t < 16) { sb0[t] = b0[t]; sb1[t] = b1[t]; sb2[t] = b2[t]; sW3[t] = W3[t]; }
    if (t == 0) sb3 = b3[0];
    __syncthreads();

    const int idx = blockIdx.x * 256 + t;
    if (idx >= N) return;

    const float2 c = reinterpret_cast<const float2*>(coords)[idx];

    float2 hv00[6], hv10[6], hv01[6], hv11[6];
    float hwx[6], hwy[6];
    #pragma unroll
    for (int l = 0; l < 6; ++l) {
        const int res = 16 << (l + 6);
        const float px = c.x * (float)res;
        const float py = c.y * (float)res;
        const float fx = floorf(px), fy = floorf(py);
        hwx[l] = px - fx;
        hwy[l] = py - fy;
        const unsigned ux = (unsigned)(int)fx, uy = (unsigned)(int)fy;
        const unsigned hy0 = uy * PRIME_Y;
        const unsigned hy1 = (uy + 1u) * PRIME_Y;
        const float2* __restrict__ tl =
            reinterpret_cast<const float2*>(table) + (size_t)(l + 6) * TSIZE;
        hv00[l] = tl[(ux ^ hy0) & (TSIZE - 1u)];
        hv10[l] = tl[((ux + 1u) ^ hy0) & (TSIZE - 1u)];
        hv01[l] = tl[(ux ^ hy1) & (TSIZE - 1u)];
        hv11[l] = tl[((ux + 1u) ^ hy1) & (TSIZE - 1u)];
    }

    float enc[24];
    #pragma unroll
    for (int lvl = 0; lvl < 6; ++lvl) {
        const int res = 16 << lvl;
        const float px = c.x * (float)res;
        const float py = c.y * (float)res;
        const float fx = floorf(px), fy = floorf(py);
        const float wx = px - fx, wy = py - fy;
        const int ix = (int)fx, iy = (int)fy;
        const int stride = res + 1;
        const int base = ix + iy * stride;
        const float2* __restrict__ tl =
            reinterpret_cast<const float2*>(table) + (size_t)lvl * TSIZE;
        const float2 v00 = tl[base];
        const float2 v10 = tl[base + 1];
        const float2 v01 = tl[base + stride];
        const float2 v11 = tl[base + stride + 1];
        const float w00 = (1.0f - wx) * (1.0f - wy);
        const float w10 = wx * (1.0f - wy);
        const float w01 = (1.0f - wx) * wy;
        const float w11 = wx * wy;
        enc[2 * lvl]     = v00.x * w00 + v10.x * w10 + v01.x * w01 + v11.x * w11;
        enc[2 * lvl + 1] = v00.y * w00 + v10.y * w10 + v01.y * w01 + v11.y * w11;
    }
    #pragma unroll
    for (int l = 0; l < 6; ++l) {
        const float wx = hwx[l], wy = hwy[l];
        const float w00 = (1.0f - wx) * (1.0f - wy);
        const float w10 = wx * (1.0f - wy);
        const float w01 = (1.0f - wx) * wy;
        const float w11 = wx * wy;
        enc[2 * (l + 6)]     = hv00[l].x * w00 + hv10[l].x * w10 + hv01[l].x * w01 + hv11[l].x * w11;
        enc[2 * (l + 6) + 1] = hv00[l].y * w00 + hv10[l].y * w10 + hv01[l].y * w01 + hv11[l].y * w11;
    }

    float h0[16];
    #pragma unroll
    for (int j = 0; j < 16; ++j) {
        float aa = sb0[j];
        #pragma unroll
        for (int k = 0; k < 24; ++k) aa += enc[k] * sW0[k * 16 + j];
        h0[j] = __sinf(300.0f * aa);
    }
    float h1[16];
    #pragma unroll
    for (int j = 0; j < 16; ++j) {
        float aa = sb1[j];
        #pragma unroll
        for (int k = 0; k < 16; ++k) aa += h0[k] * sW1[k * 16 + j];
        h1[j] = __sinf(aa);
    }
    float h2[16];
    #pragma unroll
    for (int j = 0; j < 16; ++j) {
        float aa = sb2[j];
        #pragma unroll
        for (int k = 0; k < 16; ++k) aa += h1[k] * sW2[k * 16 + j];
        h2[j] = __sinf(aa);
    }
    float o = sb3;
    #pragma unroll
    for (int k = 0; k < 16; ++k) o += h2[k] * sW3[k];
    out[idx] = o;
}

extern "C" void kernel_launch(void* const* d_in, const int* in_sizes, int n_in,
                              void* d_out, int out_size, void* d_ws, size_t ws_size,
                              hipStream_t stream) {
    const float* coords = (const float*)d_in[0];
    const float* table  = (const float*)d_in[1];
    const float* W0 = (const float*)d_in[2];
    const float* b0 = (const float*)d_in[3];
    const float* W1 = (const float*)d_in[4];
    const float* b1 = (const float*)d_in[5];
    const float* W2 = (const float*)d_in[6];
    const float* b2 = (const float*)d_in[7];
    const float* W3 = (const float*)d_in[8];
    const float* b3 = (const float*)d_in[9];
    float* out = (float*)d_out;

    const int N = in_sizes[0] / 2;  // coords is [N,2]

    const size_t tab_w = (size_t)NHASH * TSIZE / 2;      // u32 words (fp8 pairs, 12 MB)
    const size_t enc_w = (size_t)NHASH * (size_t)N;      // u32 words (6 streams, 24 MB)
    const size_t need = tab_w * 4 + enc_w * 4 + 6144;    // + wfrag
    if (ws_size >= need) {
        unsigned* wtab8 = (unsigned*)d_ws;
        unsigned* wenc = wtab8 + tab_w;
        uint4v* wfrag = (uint4v*)(wenc + enc_w);
        convert_kernel<<<4096, 256, 0, stream>>>(table, wtab8,
                                                 W0, b0, W1, b1, W2, b2, W3, wfrag);
        const int pgrid = (N + 1023) / 1024;
        for (int l = 0; l < NHASH; ++l)
            pass_kernel<<<pgrid, 256, 0, stream>>>(coords, wtab8, wenc, l, N);
        mlp_kernel<<<(N + 511) / 512, 256, 0, stream>>>(coords, table, wenc, wfrag,
                                                        b3, out, N);
    } else {
        const int block = 256;
        const int grid = (N + block - 1) / block;
        hashsiren_fused<<<grid, block, 0, stream>>>(coords, table,
                                                    W0, b0, W1, b1, W2, b2, W3, b3,
                                                    out, N);
    }
}

// Round 13
// 148.687 us; speedup vs baseline: 1.2404x; 1.0942x over previous
//
#include <hip/hip_runtime.h>
#include <math.h>

#define TSIZE (1u << 20)
#define PRIME_Y 2654435761u
#define NHASH 6   // hashed levels 6..11

typedef __attribute__((ext_vector_type(8))) short short8;     // bf16x8 MFMA frag
typedef __attribute__((ext_vector_type(4))) float f32x4;      // MFMA acc frag
typedef __attribute__((ext_vector_type(4))) float float4v;
typedef __attribute__((ext_vector_type(2))) float float2v;
typedef __attribute__((ext_vector_type(4))) unsigned uint4v;
typedef __attribute__((ext_vector_type(2))) unsigned uint2v;

struct alignas(8) f4a8 { float x, y, z, w; };   // 16B row load at 8B alignment

__device__ __forceinline__ unsigned bf16rne(unsigned u) {
    return (u + 0x7fffu + ((u >> 16) & 1u)) >> 16;   // RNE to bf16 (in low 16)
}
__device__ __forceinline__ unsigned pack_bf16x2(float a, float b) {
    return (bf16rne(__float_as_uint(a)) & 0xffffu) | (bf16rne(__float_as_uint(b)) << 16);
}
__device__ __forceinline__ float2 unpack_bf16x2(unsigned u) {
    float2 r;
    r.x = __uint_as_float(u << 16);
    r.y = __uint_as_float(u & 0xffff0000u);
    return r;
}
__device__ __forceinline__ short f2bf(float x) {
    return (short)(bf16rne(__float_as_uint(x)) & 0xffffu);
}
__device__ __forceinline__ float bf2f(short h) {
    return __uint_as_float(((unsigned)(unsigned short)h) << 16);
}
// RTZ hi/lo split packed as {hi_bits | lo_bits<<16}
__device__ __forceinline__ unsigned hilo_pack(float v) {
    const unsigned uv = __float_as_uint(v);
    const float l = v - __uint_as_float(uv & 0xffff0000u);
    return (uv >> 16) | (__float_as_uint(l) & 0xffff0000u);
}

// ---- fp8 e4m3 with x2^13 pre-scale (table values +-1e-4 -> ~0.8, all normal).
__device__ __forceinline__ unsigned fp8e(float f) {
    const float v = f * 8192.0f;
    const unsigned a = __float_as_uint(v);
    const unsigned sign = (a >> 31) << 7;
    const unsigned mag = a & 0x7fffffffu;
    const unsigned r = mag + 0x7ffffu + ((mag >> 20) & 1u);
    int u = (int)(r >> 20) - (120 << 3);
    u = (u < 0) ? 0 : u;
    return (unsigned)u | sign;
}
// decode with 2^-13 descale folded into the exponent rebias.
__device__ __forceinline__ float fp8d(unsigned u8) {
    const unsigned bits = ((u8 & 0x80u) << 24) |
                          (((u8 & 0x7fu) << 20) + (107u << 23));
    return __uint_as_float(bits);
}
__device__ __forceinline__ float2 fp8d2(unsigned u16) {   // {x:lo8, y:hi8}
    float2 r;
    r.x = fp8d(u16 & 0xffu);
    r.y = fp8d((u16 >> 8) & 0xffu);
    return r;
}

// ---- pass 0: convert hashed tables f32 -> fp8-pair (2 MiB/level); block 0
// also builds the per-lane MFMA B-fragments. NORMAL stores (must cache).
__global__ __launch_bounds__(256) void convert_kernel(
    const float* __restrict__ table, unsigned* __restrict__ wtab8,
    const float* __restrict__ W0, const float* __restrict__ b0,
    const float* __restrict__ W1, const float* __restrict__ b1,
    const float* __restrict__ W2, const float* __restrict__ b2,
    const float* __restrict__ W3,
    uint4v* __restrict__ wfrag)
{
    if (blockIdx.x == 0 && threadIdx.x < 64) {
        const int lane = threadIdx.x;
        const int n = lane & 15;
        const int kb = lane >> 4;
        short8 bf0, b1a, b1b, b2a, b2b;
        #pragma unroll
        for (int j = 0; j < 8; ++j) {
            const int k = kb * 8 + j;
            bf0[j] = (k < 24) ? f2bf(W0[k * 16 + n]) : (short)0;
            const int i = k >> 1;
            const float w1 = W1[i * 16 + n];
            const float w2 = W2[i * 16 + n];
            const short w1h = f2bf(w1), w2h = f2bf(w2);
            b1a[j] = w1h;
            b2a[j] = w2h;
            b1b[j] = (k & 1) ? (short)0 : f2bf(w1 - bf2f(w1h));
            b2b[j] = (k & 1) ? (short)0 : f2bf(w2 - bf2f(w2h));
        }
        union { short8 s; uint4v u; } cv;
        cv.s = bf0; wfrag[0 * 64 + lane] = cv.u;
        cv.s = b1a; wfrag[1 * 64 + lane] = cv.u;
        cv.s = b1b; wfrag[2 * 64 + lane] = cv.u;
        cv.s = b2a; wfrag[3 * 64 + lane] = cv.u;
        cv.s = b2b; wfrag[4 * 64 + lane] = cv.u;
        float4v bb;
        bb.x = b0[n]; bb.y = b1[n]; bb.z = b2[n]; bb.w = W3[n];
        union { float4v f; uint4v u; } cf; cf.f = bb;
        wfrag[5 * 64 + lane] = cf.u;
    }
    const size_t total4 = (size_t)NHASH * TSIZE / 2;   // float4 chunks (2 entries)
    const float4v* __restrict__ src =
        reinterpret_cast<const float4v*>(table + (size_t)6 * TSIZE * 2);
    for (size_t i = (size_t)blockIdx.x * 256 + threadIdx.x; i < total4;
         i += (size_t)gridDim.x * 256) {
        float4v v = __builtin_nontemporal_load(&src[i]);
        wtab8[i] = fp8e(v.x) | (fp8e(v.y) << 8) | (fp8e(v.z) << 16) | (fp8e(v.w) << 24);
    }
}

// ---- fused hash passes: ONE launch, level = blockIdx / blocks_per_level.
// Consecutive blocks share a level, so the ~2K resident blocks span <=2
// adjacent levels at any instant -> each XCD's L2 holds <=2 fp8 tables
// (4 MiB, fits) while level l's drain overlaps level l+1's ramp, and 5
// launch gaps disappear. Numerics identical to the per-level passes.
__global__ __launch_bounds__(256) void pass_all_kernel(
    const float* __restrict__ coords,
    const unsigned* __restrict__ wtab8,
    unsigned* __restrict__ wenc,
    int bpl, int N)
{
    const int lvl = blockIdx.x / bpl;
    const int gid = (blockIdx.x - lvl * bpl) * 256 + threadIdx.x;
    const int base = gid * 4;
    if (base >= N) return;
    const int res = 16 << (lvl + 6);
    const unsigned* __restrict__ tlp = wtab8 + ((size_t)lvl * TSIZE >> 1);  // u32 pairs
    const unsigned short* __restrict__ tl8 =
        reinterpret_cast<const unsigned short*>(tlp);
    unsigned* __restrict__ we = wenc + (size_t)lvl * N;

    if (base + 3 < N) {
        const float4v* __restrict__ c4 = reinterpret_cast<const float4v*>(coords);
        const float4v ca = __builtin_nontemporal_load(&c4[gid * 2]);
        const float4v cb = __builtin_nontemporal_load(&c4[gid * 2 + 1]);
        const float xs[4] = {ca.x, ca.z, cb.x, cb.z};
        const float ys[4] = {ca.y, ca.w, cb.y, cb.w};
        unsigned h00a[4], h01a[4], h10a[4], h11a[4], oddp[4];
        float wxs[4], wys[4];
        #pragma unroll
        for (int p = 0; p < 4; ++p) {
            const float px = xs[p] * (float)res;
            const float py = ys[p] * (float)res;
            const float fx = floorf(px), fy = floorf(py);
            wxs[p] = px - fx;
            wys[p] = py - fy;
            const unsigned ux = (unsigned)(int)fx, uy = (unsigned)(int)fy;
            const unsigned hy0 = uy * PRIME_Y;
            const unsigned hy1 = (uy + 1u) * PRIME_Y;
            h00a[p] = (ux ^ hy0) & (TSIZE - 1u);
            h01a[p] = (ux ^ hy1) & (TSIZE - 1u);
            h10a[p] = ((ux + 1u) ^ hy0) & (TSIZE - 1u);
            h11a[p] = ((ux + 1u) ^ hy1) & (TSIZE - 1u);
            oddp[p] = ux & 1u;
        }
        unsigned pr0[4], pr1[4];
        #pragma unroll
        for (int p = 0; p < 4; ++p) {
            pr0[p] = tlp[h00a[p] >> 1];
            pr1[p] = tlp[h01a[p] >> 1];
        }
        unsigned t10[4], t11[4];
        #pragma unroll
        for (int p = 0; p < 4; ++p) { t10[p] = 0u; t11[p] = 0u; }
        #pragma unroll
        for (int p = 0; p < 4; ++p) {
            if (oddp[p]) {
                t10[p] = tl8[h10a[p]];
                t11[p] = tl8[h11a[p]];
            }
        }
        uint4v r;
        #pragma unroll
        for (int p = 0; p < 4; ++p) {
            const unsigned s0 = h00a[p] & 1u;
            const unsigned s1 = h01a[p] & 1u;
            const unsigned e00 = s0 ? (pr0[p] >> 16) : (pr0[p] & 0xffffu);
            const unsigned e01 = s1 ? (pr1[p] >> 16) : (pr1[p] & 0xffffu);
            const unsigned e10 = oddp[p] ? t10[p]
                                         : (s0 ? (pr0[p] & 0xffffu) : (pr0[p] >> 16));
            const unsigned e11 = oddp[p] ? t11[p]
                                         : (s1 ? (pr1[p] & 0xffffu) : (pr1[p] >> 16));
            const float wx = wxs[p], wy = wys[p];
            const float w00 = (1.0f - wx) * (1.0f - wy);
            const float w10 = wx * (1.0f - wy);
            const float w01 = (1.0f - wx) * wy;
            const float w11 = wx * wy;
            const float2 f00 = fp8d2(e00);
            const float2 f10 = fp8d2(e10);
            const float2 f01 = fp8d2(e01);
            const float2 f11 = fp8d2(e11);
            const float e0 = f00.x * w00 + f10.x * w10 + f01.x * w01 + f11.x * w11;
            const float e1 = f00.y * w00 + f10.y * w10 + f01.y * w01 + f11.y * w11;
            r[p] = pack_bf16x2(e0, e1);
        }
        ((uint4v*)we)[gid] = r;   // normal store: enc stays cached for mlp
    } else {
        for (int p = 0; p < 4 && base + p < N; ++p) {
            const float2 c = reinterpret_cast<const float2*>(coords)[base + p];
            const float px = c.x * (float)res;
            const float py = c.y * (float)res;
            const float fx = floorf(px), fy = floorf(py);
            const float wx = px - fx, wy = py - fy;
            const unsigned ux = (unsigned)(int)fx, uy = (unsigned)(int)fy;
            const unsigned hy0 = uy * PRIME_Y;
            const unsigned hy1 = (uy + 1u) * PRIME_Y;
            const float2 v00 = fp8d2(tl8[(ux ^ hy0) & (TSIZE - 1u)]);
            const float2 v10 = fp8d2(tl8[((ux + 1u) ^ hy0) & (TSIZE - 1u)]);
            const float2 v01 = fp8d2(tl8[(ux ^ hy1) & (TSIZE - 1u)]);
            const float2 v11 = fp8d2(tl8[((ux + 1u) ^ hy1) & (TSIZE - 1u)]);
            const float w00 = (1.0f - wx) * (1.0f - wy);
            const float w10 = wx * (1.0f - wy);
            const float w01 = (1.0f - wx) * wy;
            const float w11 = wx * wy;
            const float e0 = v00.x * w00 + v10.x * w10 + v01.x * w01 + v11.x * w11;
            const float e1 = v00.y * w00 + v10.y * w10 + v01.y * w01 + v11.y * w11;
            we[base + p] = pack_bf16x2(e0, e1);
        }
    }
}

// ---- stage one point's 12 packed enc words as an MFMA A-row (K 24->32)
__device__ __forceinline__ void stage_row(char* ldsw, int lane, const unsigned* u) {
    uint4v* rowp = (uint4v*)(ldsw + lane * 80);
    uint4v r0; r0.x = u[0]; r0.y = u[1]; r0.z = u[2]; r0.w = u[3];
    uint4v r1; r1.x = u[4]; r1.y = u[5]; r1.z = u[6]; r1.w = u[7];
    uint4v r2; r2.x = u[8]; r2.y = u[9]; r2.z = u[10]; r2.w = u[11];
    uint4v r3; r3.x = 0u; r3.y = 0u; r3.z = 0u; r3.w = 0u;  // keep: no NaN*0
    rowp[0] = r0; rowp[1] = r1; rowp[2] = r2; rowp[3] = r3;
}

// ---- final: dense levels + hashed enc streams + MFMA SIREN MLP.
// 2 points/thread, no barriers (wave-private LDS regions).
__global__ __launch_bounds__(256) void mlp_kernel(
    const float* __restrict__ coords,
    const float* __restrict__ table,
    const unsigned* __restrict__ wenc,
    const uint4v* __restrict__ wfrag,
    const float* __restrict__ b3p,
    float* __restrict__ out, int N)
{
    __shared__ char lds[40960];             // 4 waves * 2 tiles * 5120 B
    const int t = threadIdx.x;
    const int lane = t & 63;
    const int wv = t >> 6;
    const int n = lane & 15;
    const int kb = lane >> 4;
    char* lds0 = lds + wv * 10240;
    char* lds1 = lds0 + 5120;

    union { short8 s; uint4v u; } w0u, w1au, w1bu, w2au, w2bu;
    w0u.u  = wfrag[0 * 64 + lane];
    w1au.u = wfrag[1 * 64 + lane];
    w1bu.u = wfrag[2 * 64 + lane];
    w2au.u = wfrag[3 * 64 + lane];
    w2bu.u = wfrag[4 * 64 + lane];
    const short8 bf0 = w0u.s, b1a = w1au.s, b1b = w1bu.s, b2a = w2au.s, b2b = w2bu.s;
    union { float4v f; uint4v u; } cf;
    cf.u = wfrag[5 * 64 + lane];
    const float b0n = cf.f.x, b1n = cf.f.y, b2n = cf.f.z, w3n = cf.f.w;
    const float b3s = b3p[0];

    const int base = blockIdx.x * 512 + wv * 128;   // 4 waves * 128 pts
    const int idx0 = base + lane;
    const int idx1 = idx0 + 64;
    const int i0 = (idx0 < N) ? idx0 : (N - 1);
    const int i1 = (idx1 < N) ? idx1 : (N - 1);

    unsigned u0[12], u1[12];
    #pragma unroll
    for (int l = 0; l < NHASH; ++l) {
        u0[6 + l] = wenc[(size_t)l * N + i0];
        u1[6 + l] = wenc[(size_t)l * N + i1];
    }
    const float2v cA = reinterpret_cast<const float2v*>(coords)[i0];
    const float2v cB = reinterpret_cast<const float2v*>(coords)[i1];

    #pragma unroll
    for (int lvl = 0; lvl < 6; ++lvl) {
        const int res = 16 << lvl;
        const int stride = res + 1;
        const float* __restrict__ tl = table + (size_t)lvl * TSIZE * 2u;
        {
            const float px = cA.x * (float)res;
            const float py = cA.y * (float)res;
            const float fx = floorf(px), fy = floorf(py);
            const float wx = px - fx, wy = py - fy;
            const int b = (int)fx + (int)fy * stride;
            const f4a8 r0 = *reinterpret_cast<const f4a8*>(tl + 2 * (size_t)b);
            const f4a8 r1 = *reinterpret_cast<const f4a8*>(tl + 2 * (size_t)(b + stride));
            const float w00 = (1.0f - wx) * (1.0f - wy);
            const float w10 = wx * (1.0f - wy);
            const float w01 = (1.0f - wx) * wy;
            const float w11 = wx * wy;
            u0[lvl] = pack_bf16x2(r0.x * w00 + r0.z * w10 + r1.x * w01 + r1.z * w11,
                                  r0.y * w00 + r0.w * w10 + r1.y * w01 + r1.w * w11);
        }
        {
            const float px = cB.x * (float)res;
            const float py = cB.y * (float)res;
            const float fx = floorf(px), fy = floorf(py);
            const float wx = px - fx, wy = py - fy;
            const int b = (int)fx + (int)fy * stride;
            const f4a8 r0 = *reinterpret_cast<const f4a8*>(tl + 2 * (size_t)b);
            const f4a8 r1 = *reinterpret_cast<const f4a8*>(tl + 2 * (size_t)(b + stride));
            const float w00 = (1.0f - wx) * (1.0f - wy);
            const float w10 = wx * (1.0f - wy);
            const float w01 = (1.0f - wx) * wy;
            const float w11 = wx * wy;
            u1[lvl] = pack_bf16x2(r0.x * w00 + r0.z * w10 + r1.x * w01 + r1.z * w11,
                                  r0.y * w00 + r0.w * w10 + r1.y * w01 + r1.w * w11);
        }
    }

    stage_row(lds0, lane, u0);
    stage_row(lds1, lane, u1);

    short8 a0[4], a1[4];
    #pragma unroll
    for (int m = 0; m < 4; ++m) {
        a0[m] = *(const short8*)(lds0 + (m * 16 + n) * 80 + kb * 16);
        a1[m] = *(const short8*)(lds1 + (m * 16 + n) * 80 + kb * 16);
    }

    const f32x4 z = {0.f, 0.f, 0.f, 0.f};
    f32x4 acc0[4], acc1[4];
    #pragma unroll
    for (int m = 0; m < 4; ++m) {
        acc0[m] = __builtin_amdgcn_mfma_f32_16x16x32_bf16(a0[m], bf0, z, 0, 0, 0);
        acc1[m] = __builtin_amdgcn_mfma_f32_16x16x32_bf16(a1[m], bf0, z, 0, 0, 0);
    }

    unsigned* hp0 = (unsigned*)lds0;   // rows of 20 words; word n = {hi|lo<<16}
    unsigned* hp1 = (unsigned*)lds1;

    // ---- layer 1
    #pragma unroll
    for (int m = 0; m < 4; ++m) {
        #pragma unroll
        for (int r = 0; r < 4; ++r) {
            const int row = m * 16 + kb * 4 + r;
            hp0[row * 20 + n] = hilo_pack(__sinf(300.0f * (acc0[m][r] + b0n)));
            hp1[row * 20 + n] = hilo_pack(__sinf(300.0f * (acc1[m][r] + b0n)));
        }
    }
    #pragma unroll
    for (int m = 0; m < 4; ++m) {
        a0[m] = *(const short8*)(lds0 + (m * 16 + n) * 80 + kb * 16);
        a1[m] = *(const short8*)(lds1 + (m * 16 + n) * 80 + kb * 16);
    }
    #pragma unroll
    for (int m = 0; m < 4; ++m) {
        f32x4 p0 = __builtin_amdgcn_mfma_f32_16x16x32_bf16(a0[m], b1a, z, 0, 0, 0);
        acc0[m] = __builtin_amdgcn_mfma_f32_16x16x32_bf16(a0[m], b1b, p0, 0, 0, 0);
        f32x4 p1 = __builtin_amdgcn_mfma_f32_16x16x32_bf16(a1[m], b1a, z, 0, 0, 0);
        acc1[m] = __builtin_amdgcn_mfma_f32_16x16x32_bf16(a1[m], b1b, p1, 0, 0, 0);
    }

    // ---- layer 2
    #pragma unroll
    for (int m = 0; m < 4; ++m) {
        #pragma unroll
        for (int r = 0; r < 4; ++r) {
            const int row = m * 16 + kb * 4 + r;
            hp0[row * 20 + n] = hilo_pack(__sinf(acc0[m][r] + b1n));
            hp1[row * 20 + n] = hilo_pack(__sinf(acc1[m][r] + b1n));
        }
    }
    #pragma unroll
    for (int m = 0; m < 4; ++m) {
        a0[m] = *(const short8*)(lds0 + (m * 16 + n) * 80 + kb * 16);
        a1[m] = *(const short8*)(lds1 + (m * 16 + n) * 80 + kb * 16);
    }
    #pragma unroll
    for (int m = 0; m < 4; ++m) {
        f32x4 p0 = __builtin_amdgcn_mfma_f32_16x16x32_bf16(a0[m], b2a, z, 0, 0, 0);
        acc0[m] = __builtin_amdgcn_mfma_f32_16x16x32_bf16(a0[m], b2b, p0, 0, 0, 0);
        f32x4 p1 = __builtin_amdgcn_mfma_f32_16x16x32_bf16(a1[m], b2a, z, 0, 0, 0);
        acc1[m] = __builtin_amdgcn_mfma_f32_16x16x32_bf16(a1[m], b2b, p1, 0, 0, 0);
    }

    // ---- layer 3 (16->1) in f32: shuffle-reduce over the 16 n-lanes
    const int m2 = n >> 2, r2 = n & 3;
    float ov0 = 0.f, ov1 = 0.f;
    #pragma unroll
    for (int m = 0; m < 4; ++m) {
        #pragma unroll
        for (int r = 0; r < 4; ++r) {
            float v0 = __sinf(acc0[m][r] + b2n) * w3n;
            float v1 = __sinf(acc1[m][r] + b2n) * w3n;
            v0 += __shfl_xor(v0, 1);  v1 += __shfl_xor(v1, 1);
            v0 += __shfl_xor(v0, 2);  v1 += __shfl_xor(v1, 2);
            v0 += __shfl_xor(v0, 4);  v1 += __shfl_xor(v1, 4);
            v0 += __shfl_xor(v0, 8);  v1 += __shfl_xor(v1, 8);
            if (m == m2 && r == r2) { ov0 = v0; ov1 = v1; }
        }
    }
    const int g0 = base + m2 * 16 + kb * 4 + r2;
    const int g1 = g0 + 64;
    if (g0 < N) __builtin_nontemporal_store(ov0 + b3s, &out[g0]);
    if (g1 < N) __builtin_nontemporal_store(ov1 + b3s, &out[g1]);
}

// ---- fallback: R1 fused kernel (known-good) for small ws
__global__ __launch_bounds__(256) void hashsiren_fused(
    const float* __restrict__ coords,
    const float* __restrict__ table,
    const float* __restrict__ W0, const float* __restrict__ b0,
    const float* __restrict__ W1, const float* __restrict__ b1,
    const float* __restrict__ W2, const float* __restrict__ b2,
    const float* __restrict__ W3, const float* __restrict__ b3,
    float* __restrict__ out, int N)
{
    __shared__ float sW0[384];
    __shared__ float sW1[256];
    __shared__ float sW2[256];
    __shared__ float sb0[16], sb1[16], sb2[16], sW3[16];
    __shared__ float sb3;

    const int t = threadIdx.x;
    for (int i = t; i < 384; i += 256) sW0[i] = W0[i];
    sW1[t] = W1[t];
    sW2[t] = W2[t];
    if (t < 16) { sb0[t] = b0[t]; sb1[t] = b1[t]; sb2[t] = b2[t]; sW3[t] = W3[t]; }
    if (t == 0) sb3 = b3[0];
    __syncthreads();

    const int idx = blockIdx.x * 256 + t;
    if (idx >= N) return;

    const float2 c = reinterpret_cast<const float2*>(coords)[idx];

    float2 hv00[6], hv10[6], hv01[6], hv11[6];
    float hwx[6], hwy[6];
    #pragma unroll
    for (int l = 0; l < 6; ++l) {
        const int res = 16 << (l + 6);
        const float px = c.x * (float)res;
        const float py = c.y * (float)res;
        const float fx = floorf(px), fy = floorf(py);
        hwx[l] = px - fx;
        hwy[l] = py - fy;
        const unsigned ux = (unsigned)(int)fx, uy = (unsigned)(int)fy;
        const unsigned hy0 = uy * PRIME_Y;
        const unsigned hy1 = (uy + 1u) * PRIME_Y;
        const float2* __restrict__ tl =
            reinterpret_cast<const float2*>(table) + (size_t)(l + 6) * TSIZE;
        hv00[l] = tl[(ux ^ hy0) & (TSIZE - 1u)];
        hv10[l] = tl[((ux + 1u) ^ hy0) & (TSIZE - 1u)];
        hv01[l] = tl[(ux ^ hy1) & (TSIZE - 1u)];
        hv11[l] = tl[((ux + 1u) ^ hy1) & (TSIZE - 1u)];
    }

    float enc[24];
    #pragma unroll
    for (int lvl = 0; lvl < 6; ++lvl) {
        const int res = 16 << lvl;
        const float px = c.x * (float)res;
        const float py = c.y * (float)res;
        const float fx = floorf(px), fy = floorf(py);
        const float wx = px - fx, wy = py - fy;
        const int ix = (int)fx, iy = (int)fy;
        const int stride = res + 1;
        const int base = ix + iy * stride;
        const float2* __restrict__ tl =
            reinterpret_cast<const float2*>(table) + (size_t)lvl * TSIZE;
        const float2 v00 = tl[base];
        const float2 v10 = tl[base + 1];
        const float2 v01 = tl[base + stride];
        const float2 v11 = tl[base + stride + 1];
        const float w00 = (1.0f - wx) * (1.0f - wy);
        const float w10 = wx * (1.0f - wy);
        const float w01 = (1.0f - wx) * wy;
        const float w11 = wx * wy;
        enc[2 * lvl]     = v00.x * w00 + v10.x * w10 + v01.x * w01 + v11.x * w11;
        enc[2 * lvl + 1] = v00.y * w00 + v10.y * w10 + v01.y * w01 + v11.y * w11;
    }
    #pragma unroll
    for (int l = 0; l < 6; ++l) {
        const float wx = hwx[l], wy = hwy[l];
        const float w00 = (1.0f - wx) * (1.0f - wy);
        const float w10 = wx * (1.0f - wy);
        const float w01 = (1.0f - wx) * wy;
        const float w11 = wx * wy;
        enc[2 * (l + 6)]     = hv00[l].x * w00 + hv10[l].x * w10 + hv01[l].x * w01 + hv11[l].x * w11;
        enc[2 * (l + 6) + 1] = hv00[l].y * w00 + hv10[l].y * w10 + hv01[l].y * w01 + hv11[l].y * w11;
    }

    float h0[16];
    #pragma unroll
    for (int j = 0; j < 16; ++j) {
        float aa = sb0[j];
        #pragma unroll
        for (int k = 0; k < 24; ++k) aa += enc[k] * sW0[k * 16 + j];
        h0[j] = __sinf(300.0f * aa);
    }
    float h1[16];
    #pragma unroll
    for (int j = 0; j < 16; ++j) {
        float aa = sb1[j];
        #pragma unroll
        for (int k = 0; k < 16; ++k) aa += h0[k] * sW1[k * 16 + j];
        h1[j] = __sinf(aa);
    }
    float h2[16];
    #pragma unroll
    for (int j = 0; j < 16; ++j) {
        float aa = sb2[j];
        #pragma unroll
        for (int k = 0; k < 16; ++k) aa += h1[k] * sW2[k * 16 + j];
        h2[j] = __sinf(aa);
    }
    float o = sb3;
    #pragma unroll
    for (int k = 0; k < 16; ++k) o += h2[k] * sW3[k];
    out[idx] = o;
}

extern "C" void kernel_launch(void* const* d_in, const int* in_sizes, int n_in,
                              void* d_out, int out_size, void* d_ws, size_t ws_size,
                              hipStream_t stream) {
    const float* coords = (const float*)d_in[0];
    const float* table  = (const float*)d_in[1];
    const float* W0 = (const float*)d_in[2];
    const float* b0 = (const float*)d_in[3];
    const float* W1 = (const float*)d_in[4];
    const float* b1 = (const float*)d_in[5];
    const float* W2 = (const float*)d_in[6];
    const float* b2 = (const float*)d_in[7];
    const float* W3 = (const float*)d_in[8];
    const float* b3 = (const float*)d_in[9];
    float* out = (float*)d_out;

    const int N = in_sizes[0] / 2;  // coords is [N,2]

    const size_t tab_w = (size_t)NHASH * TSIZE / 2;      // u32 words (fp8 pairs, 12 MB)
    const size_t enc_w = (size_t)NHASH * (size_t)N;      // u32 words (6 streams, 24 MB)
    const size_t need = tab_w * 4 + enc_w * 4 + 6144;    // + wfrag
    if (ws_size >= need) {
        unsigned* wtab8 = (unsigned*)d_ws;
        unsigned* wenc = wtab8 + tab_w;
        uint4v* wfrag = (uint4v*)(wenc + enc_w);
        convert_kernel<<<4096, 256, 0, stream>>>(table, wtab8,
                                                 W0, b0, W1, b1, W2, b2, W3, wfrag);
        const int bpl = (N + 1023) / 1024;   // blocks per level
        pass_all_kernel<<<NHASH * bpl, 256, 0, stream>>>(coords, wtab8, wenc, bpl, N);
        mlp_kernel<<<(N + 511) / 512, 256, 0, stream>>>(coords, table, wenc, wfrag,
                                                        b3, out, N);
    } else {
        const int block = 256;
        const int grid = (N + block - 1) / block;
        hashsiren_fused<<<grid, block, 0, stream>>>(coords, table,
                                                    W0, b0, W1, b1, W2, b2, W3, b3,
                                                    out, N);
    }
}

// Round 14
// 148.348 us; speedup vs baseline: 1.2432x; 1.0023x over previous
//
#include <hip/hip_runtime.h>
#include <math.h>

#define TSIZE (1u << 20)
#define PRIME_Y 2654435761u
#define NHASH 6   // hashed levels 6..11
#define NDENSE_CELLS 351462   // sum (res+1)^2, res=16..512
#define NDENSE_PAD   351488

typedef __attribute__((ext_vector_type(8))) short short8;     // bf16x8 MFMA frag
typedef __attribute__((ext_vector_type(4))) float f32x4;      // MFMA acc frag
typedef __attribute__((ext_vector_type(4))) float float4v;
typedef __attribute__((ext_vector_type(2))) float float2v;
typedef __attribute__((ext_vector_type(4))) unsigned uint4v;
typedef __attribute__((ext_vector_type(2))) unsigned uint2v;

__device__ __forceinline__ unsigned bf16rne(unsigned u) {
    return (u + 0x7fffu + ((u >> 16) & 1u)) >> 16;   // RNE to bf16 (in low 16)
}
__device__ __forceinline__ unsigned pack_bf16x2(float a, float b) {
    return (bf16rne(__float_as_uint(a)) & 0xffffu) | (bf16rne(__float_as_uint(b)) << 16);
}
__device__ __forceinline__ float2 unpack_bf16x2(unsigned u) {
    float2 r;
    r.x = __uint_as_float(u << 16);
    r.y = __uint_as_float(u & 0xffff0000u);
    return r;
}
__device__ __forceinline__ short f2bf(float x) {
    return (short)(bf16rne(__float_as_uint(x)) & 0xffffu);
}
__device__ __forceinline__ float bf2f(short h) {
    return __uint_as_float(((unsigned)(unsigned short)h) << 16);
}
// RTZ hi/lo split packed as {hi_bits | lo_bits<<16}
__device__ __forceinline__ unsigned hilo_pack(float v) {
    const unsigned uv = __float_as_uint(v);
    const float l = v - __uint_as_float(uv & 0xffff0000u);
    return (uv >> 16) | (__float_as_uint(l) & 0xffff0000u);
}

// ---- fp8 e4m3 with x2^13 pre-scale (hashed-table values +-1e-4 -> ~0.8).
__device__ __forceinline__ unsigned fp8e(float f) {
    const float v = f * 8192.0f;
    const unsigned a = __float_as_uint(v);
    const unsigned sign = (a >> 31) << 7;
    const unsigned mag = a & 0x7fffffffu;
    const unsigned r = mag + 0x7ffffu + ((mag >> 20) & 1u);
    int u = (int)(r >> 20) - (120 << 3);
    u = (u < 0) ? 0 : u;
    return (unsigned)u | sign;
}
__device__ __forceinline__ float fp8d(unsigned u8) {
    const unsigned bits = ((u8 & 0x80u) << 24) |
                          (((u8 & 0x7fu) << 20) + (107u << 23));
    return __uint_as_float(bits);
}
__device__ __forceinline__ float2 fp8d2(unsigned u16) {   // {x:lo8, y:hi8}
    float2 r;
    r.x = fp8d(u16 & 0xffu);
    r.y = fp8d((u16 >> 8) & 0xffu);
    return r;
}

// ---- pass 0: hashed tables f32 -> fp8-pair (2 MiB/level, L2-resident);
// dense tables -> duplicated-pair bf16 cells (cell b = {v[b], v[b+1]}, one
// aligned 8B load per interp row); block 0 builds MFMA B-fragments.
__global__ __launch_bounds__(256) void convert_kernel(
    const float* __restrict__ table, unsigned* __restrict__ wtab8,
    unsigned* __restrict__ wdense,
    const float* __restrict__ W0, const float* __restrict__ b0,
    const float* __restrict__ W1, const float* __restrict__ b1,
    const float* __restrict__ W2, const float* __restrict__ b2,
    const float* __restrict__ W3,
    uint4v* __restrict__ wfrag)
{
    if (blockIdx.x == 0 && threadIdx.x < 64) {
        const int lane = threadIdx.x;
        const int n = lane & 15;
        const int kb = lane >> 4;
        short8 bf0, b1a, b1b, b2a, b2b;
        #pragma unroll
        for (int j = 0; j < 8; ++j) {
            const int k = kb * 8 + j;
            bf0[j] = (k < 24) ? f2bf(W0[k * 16 + n]) : (short)0;
            const int i = k >> 1;
            const float w1 = W1[i * 16 + n];
            const float w2 = W2[i * 16 + n];
            const short w1h = f2bf(w1), w2h = f2bf(w2);
            b1a[j] = w1h;
            b2a[j] = w2h;
            b1b[j] = (k & 1) ? (short)0 : f2bf(w1 - bf2f(w1h));
            b2b[j] = (k & 1) ? (short)0 : f2bf(w2 - bf2f(w2h));
        }
        union { short8 s; uint4v u; } cv;
        cv.s = bf0; wfrag[0 * 64 + lane] = cv.u;
        cv.s = b1a; wfrag[1 * 64 + lane] = cv.u;
        cv.s = b1b; wfrag[2 * 64 + lane] = cv.u;
        cv.s = b2a; wfrag[3 * 64 + lane] = cv.u;
        cv.s = b2b; wfrag[4 * 64 + lane] = cv.u;
        float4v bb;
        bb.x = b0[n]; bb.y = b1[n]; bb.z = b2[n]; bb.w = W3[n];
        union { float4v f; uint4v u; } cf; cf.f = bb;
        wfrag[5 * 64 + lane] = cf.u;
    }
    // hashed levels -> fp8 pairs
    const size_t total4 = (size_t)NHASH * TSIZE / 2;   // float4 chunks (2 entries)
    const float4v* __restrict__ src =
        reinterpret_cast<const float4v*>(table + (size_t)6 * TSIZE * 2);
    for (size_t i = (size_t)blockIdx.x * 256 + threadIdx.x; i < total4;
         i += (size_t)gridDim.x * 256) {
        float4v v = __builtin_nontemporal_load(&src[i]);
        wtab8[i] = fp8e(v.x) | (fp8e(v.y) << 8) | (fp8e(v.z) << 16) | (fp8e(v.w) << 24);
    }
    // dense levels -> duplicated-pair bf16 cells
    const int DCUM[7] = {0, 289, 1378, 5603, 22244, 88293, 351462};
    for (int i = blockIdx.x * 256 + threadIdx.x; i < NDENSE_CELLS;
         i += gridDim.x * 256) {
        int lvl = 0;
        #pragma unroll
        for (int l = 1; l < 6; ++l) lvl += (i >= DCUM[l]);
        const int e = i - DCUM[lvl];
        const int sz = DCUM[lvl + 1] - DCUM[lvl];
        const float* __restrict__ dsrc = table + (size_t)lvl * TSIZE * 2u;
        const int e1 = (e + 1 < sz) ? e + 1 : e;
        uint2v o;
        o.x = pack_bf16x2(dsrc[2 * e], dsrc[2 * e + 1]);
        o.y = pack_bf16x2(dsrc[2 * e1], dsrc[2 * e1 + 1]);
        reinterpret_cast<uint2v*>(wdense)[i] = o;
    }
}

// ---- fused hash passes: ONE launch, level = blockIdx / bpl (consecutive
// blocks share a level -> <=2 tables live per XCD L2 at any instant).
__global__ __launch_bounds__(256) void pass_all_kernel(
    const float* __restrict__ coords,
    const unsigned* __restrict__ wtab8,
    unsigned* __restrict__ wenc,
    int bpl, int N)
{
    const int lvl = blockIdx.x / bpl;
    const int gid = (blockIdx.x - lvl * bpl) * 256 + threadIdx.x;
    const int base = gid * 4;
    if (base >= N) return;
    const int res = 16 << (lvl + 6);
    const unsigned* __restrict__ tlp = wtab8 + ((size_t)lvl * TSIZE >> 1);  // u32 pairs
    const unsigned short* __restrict__ tl8 =
        reinterpret_cast<const unsigned short*>(tlp);
    unsigned* __restrict__ we = wenc + (size_t)lvl * N;

    if (base + 3 < N) {
        const float4v* __restrict__ c4 = reinterpret_cast<const float4v*>(coords);
        const float4v ca = __builtin_nontemporal_load(&c4[gid * 2]);
        const float4v cb = __builtin_nontemporal_load(&c4[gid * 2 + 1]);
        const float xs[4] = {ca.x, ca.z, cb.x, cb.z};
        const float ys[4] = {ca.y, ca.w, cb.y, cb.w};
        unsigned h00a[4], h01a[4], h10a[4], h11a[4], oddp[4];
        float wxs[4], wys[4];
        #pragma unroll
        for (int p = 0; p < 4; ++p) {
            const float px = xs[p] * (float)res;
            const float py = ys[p] * (float)res;
            const float fx = floorf(px), fy = floorf(py);
            wxs[p] = px - fx;
            wys[p] = py - fy;
            const unsigned ux = (unsigned)(int)fx, uy = (unsigned)(int)fy;
            const unsigned hy0 = uy * PRIME_Y;
            const unsigned hy1 = (uy + 1u) * PRIME_Y;
            h00a[p] = (ux ^ hy0) & (TSIZE - 1u);
            h01a[p] = (ux ^ hy1) & (TSIZE - 1u);
            h10a[p] = ((ux + 1u) ^ hy0) & (TSIZE - 1u);
            h11a[p] = ((ux + 1u) ^ hy1) & (TSIZE - 1u);
            oddp[p] = ux & 1u;
        }
        unsigned pr0[4], pr1[4];
        #pragma unroll
        for (int p = 0; p < 4; ++p) {
            pr0[p] = tlp[h00a[p] >> 1];
            pr1[p] = tlp[h01a[p] >> 1];
        }
        unsigned t10[4], t11[4];
        #pragma unroll
        for (int p = 0; p < 4; ++p) { t10[p] = 0u; t11[p] = 0u; }
        #pragma unroll
        for (int p = 0; p < 4; ++p) {
            if (oddp[p]) {
                t10[p] = tl8[h10a[p]];
                t11[p] = tl8[h11a[p]];
            }
        }
        uint4v r;
        #pragma unroll
        for (int p = 0; p < 4; ++p) {
            const unsigned s0 = h00a[p] & 1u;
            const unsigned s1 = h01a[p] & 1u;
            const unsigned e00 = s0 ? (pr0[p] >> 16) : (pr0[p] & 0xffffu);
            const unsigned e01 = s1 ? (pr1[p] >> 16) : (pr1[p] & 0xffffu);
            const unsigned e10 = oddp[p] ? t10[p]
                                         : (s0 ? (pr0[p] & 0xffffu) : (pr0[p] >> 16));
            const unsigned e11 = oddp[p] ? t11[p]
                                         : (s1 ? (pr1[p] & 0xffffu) : (pr1[p] >> 16));
            const float wx = wxs[p], wy = wys[p];
            const float w00 = (1.0f - wx) * (1.0f - wy);
            const float w10 = wx * (1.0f - wy);
            const float w01 = (1.0f - wx) * wy;
            const float w11 = wx * wy;
            const float2 f00 = fp8d2(e00);
            const float2 f10 = fp8d2(e10);
            const float2 f01 = fp8d2(e01);
            const float2 f11 = fp8d2(e11);
            const float e0 = f00.x * w00 + f10.x * w10 + f01.x * w01 + f11.x * w11;
            const float e1 = f00.y * w00 + f10.y * w10 + f01.y * w01 + f11.y * w11;
            r[p] = pack_bf16x2(e0, e1);
        }
        ((uint4v*)we)[gid] = r;   // normal store: enc stays cached for mlp
    } else {
        for (int p = 0; p < 4 && base + p < N; ++p) {
            const float2 c = reinterpret_cast<const float2*>(coords)[base + p];
            const float px = c.x * (float)res;
            const float py = c.y * (float)res;
            const float fx = floorf(px), fy = floorf(py);
            const float wx = px - fx, wy = py - fy;
            const unsigned ux = (unsigned)(int)fx, uy = (unsigned)(int)fy;
            const unsigned hy0 = uy * PRIME_Y;
            const unsigned hy1 = (uy + 1u) * PRIME_Y;
            const float2 v00 = fp8d2(tl8[(ux ^ hy0) & (TSIZE - 1u)]);
            const float2 v10 = fp8d2(tl8[((ux + 1u) ^ hy0) & (TSIZE - 1u)]);
            const float2 v01 = fp8d2(tl8[(ux ^ hy1) & (TSIZE - 1u)]);
            const float2 v11 = fp8d2(tl8[((ux + 1u) ^ hy1) & (TSIZE - 1u)]);
            const float w00 = (1.0f - wx) * (1.0f - wy);
            const float w10 = wx * (1.0f - wy);
            const float w01 = (1.0f - wx) * wy;
            const float w11 = wx * wy;
            const float e0 = v00.x * w00 + v10.x * w10 + v01.x * w01 + v11.x * w11;
            const float e1 = v00.y * w00 + v10.y * w10 + v01.y * w01 + v11.y * w11;
            we[base + p] = pack_bf16x2(e0, e1);
        }
    }
}

// ---- stage one point's 12 packed enc words as an MFMA A-row (K 24->32)
__device__ __forceinline__ void stage_row(char* ldsw, int lane, const unsigned* u) {
    uint4v* rowp = (uint4v*)(ldsw + lane * 80);
    uint4v r0; r0.x = u[0]; r0.y = u[1]; r0.z = u[2]; r0.w = u[3];
    uint4v r1; r1.x = u[4]; r1.y = u[5]; r1.z = u[6]; r1.w = u[7];
    uint4v r2; r2.x = u[8]; r2.y = u[9]; r2.z = u[10]; r2.w = u[11];
    uint4v r3; r3.x = 0u; r3.y = 0u; r3.z = 0u; r3.w = 0u;  // keep: no NaN*0
    rowp[0] = r0; rowp[1] = r1; rowp[2] = r2; rowp[3] = r3;
}

// ---- final: dense (bf16 dup-pair cells) + hashed enc streams + MFMA MLP.
// ADJACENT-point pairing: thread handles points (2i, 2i+1) -> 1 float4 coord
// load, 6 uint2 enc loads, 1 float2 out store. Tile0 = even points, tile1 =
// odd points of the wave's 128-point range. No barriers (wave-private LDS).
__global__ __launch_bounds__(256) void mlp_kernel(
    const float* __restrict__ coords,
    const unsigned* __restrict__ wdense,
    const unsigned* __restrict__ wenc,
    const uint4v* __restrict__ wfrag,
    const float* __restrict__ b3p,
    float* __restrict__ out, int N)
{
    __shared__ char lds[40960];             // 4 waves * 2 tiles * 5120 B
    const int t = threadIdx.x;
    const int lane = t & 63;
    const int wv = t >> 6;
    const int n = lane & 15;
    const int kb = lane >> 4;
    char* lds0 = lds + wv * 10240;
    char* lds1 = lds0 + 5120;

    union { short8 s; uint4v u; } w0u, w1au, w1bu, w2au, w2bu;
    w0u.u  = wfrag[0 * 64 + lane];
    w1au.u = wfrag[1 * 64 + lane];
    w1bu.u = wfrag[2 * 64 + lane];
    w2au.u = wfrag[3 * 64 + lane];
    w2bu.u = wfrag[4 * 64 + lane];
    const short8 bf0 = w0u.s, b1a = w1au.s, b1b = w1bu.s, b2a = w2au.s, b2b = w2bu.s;
    union { float4v f; uint4v u; } cf;
    cf.u = wfrag[5 * 64 + lane];
    const float b0n = cf.f.x, b1n = cf.f.y, b2n = cf.f.z, w3n = cf.f.w;
    const float b3s = b3p[0];

    const int wbase = blockIdx.x * 512 + wv * 128;   // 4 waves * 128 pts
    int i0 = wbase + 2 * lane;
    if (i0 > N - 2) i0 = (N - 2) & ~1;               // clamp, keep even

    // 6 paired enc loads ({even,odd} in one aligned uint2)
    unsigned u0[12], u1[12];
    #pragma unroll
    for (int l = 0; l < NHASH; ++l) {
        const uint2v ev = *reinterpret_cast<const uint2v*>(wenc + (size_t)l * N + i0);
        u0[6 + l] = ev.x;
        u1[6 + l] = ev.y;
    }
    // paired coords: one float4 covers both points
    const float4v cc = reinterpret_cast<const float4v*>(coords)[i0 >> 1];
    const float2 cA = {cc.x, cc.y};
    const float2 cB = {cc.z, cc.w};

    const int DC[6] = {0, 289, 1378, 5603, 22244, 88293};
    #pragma unroll
    for (int lvl = 0; lvl < 6; ++lvl) {
        const int res = 16 << lvl;
        const int stride = res + 1;
        const uint2v* __restrict__ td =
            reinterpret_cast<const uint2v*>(wdense) + DC[lvl];
        {
            const float px = cA.x * (float)res;
            const float py = cA.y * (float)res;
            const float fx = floorf(px), fy = floorf(py);
            const float wx = px - fx, wy = py - fy;
            const int b = (int)fx + (int)fy * stride;
            const uint2v r0 = td[b];                 // {v[b], v[b+1]} bf16x2 each
            const uint2v r1 = td[b + stride];
            const float2 v00 = unpack_bf16x2(r0.x);
            const float2 v10 = unpack_bf16x2(r0.y);
            const float2 v01 = unpack_bf16x2(r1.x);
            const float2 v11 = unpack_bf16x2(r1.y);
            const float w00 = (1.0f - wx) * (1.0f - wy);
            const float w10 = wx * (1.0f - wy);
            const float w01 = (1.0f - wx) * wy;
            const float w11 = wx * wy;
            u0[lvl] = pack_bf16x2(v00.x * w00 + v10.x * w10 + v01.x * w01 + v11.x * w11,
                                  v00.y * w00 + v10.y * w10 + v01.y * w01 + v11.y * w11);
        }
        {
            const float px = cB.x * (float)res;
            const float py = cB.y * (float)res;
            const float fx = floorf(px), fy = floorf(py);
            const float wx = px - fx, wy = py - fy;
            const int b = (int)fx + (int)fy * stride;
            const uint2v r0 = td[b];
            const uint2v r1 = td[b + stride];
            const float2 v00 = unpack_bf16x2(r0.x);
            const float2 v10 = unpack_bf16x2(r0.y);
            const float2 v01 = unpack_bf16x2(r1.x);
            const float2 v11 = unpack_bf16x2(r1.y);
            const float w00 = (1.0f - wx) * (1.0f - wy);
            const float w10 = wx * (1.0f - wy);
            const float w01 = (1.0f - wx) * wy;
            const float w11 = wx * wy;
            u1[lvl] = pack_bf16x2(v00.x * w00 + v10.x * w10 + v01.x * w01 + v11.x * w11,
                                  v00.y * w00 + v10.y * w10 + v01.y * w01 + v11.y * w11);
        }
    }

    stage_row(lds0, lane, u0);
    stage_row(lds1, lane, u1);

    short8 a0[4], a1[4];
    #pragma unroll
    for (int m = 0; m < 4; ++m) {
        a0[m] = *(const short8*)(lds0 + (m * 16 + n) * 80 + kb * 16);
        a1[m] = *(const short8*)(lds1 + (m * 16 + n) * 80 + kb * 16);
    }

    const f32x4 z = {0.f, 0.f, 0.f, 0.f};
    f32x4 acc0[4], acc1[4];
    #pragma unroll
    for (int m = 0; m < 4; ++m) {
        acc0[m] = __builtin_amdgcn_mfma_f32_16x16x32_bf16(a0[m], bf0, z, 0, 0, 0);
        acc1[m] = __builtin_amdgcn_mfma_f32_16x16x32_bf16(a1[m], bf0, z, 0, 0, 0);
    }

    unsigned* hp0 = (unsigned*)lds0;   // rows of 20 words; word n = {hi|lo<<16}
    unsigned* hp1 = (unsigned*)lds1;

    // ---- layer 1
    #pragma unroll
    for (int m = 0; m < 4; ++m) {
        #pragma unroll
        for (int r = 0; r < 4; ++r) {
            const int row = m * 16 + kb * 4 + r;
            hp0[row * 20 + n] = hilo_pack(__sinf(300.0f * (acc0[m][r] + b0n)));
            hp1[row * 20 + n] = hilo_pack(__sinf(300.0f * (acc1[m][r] + b0n)));
        }
    }
    #pragma unroll
    for (int m = 0; m < 4; ++m) {
        a0[m] = *(const short8*)(lds0 + (m * 16 + n) * 80 + kb * 16);
        a1[m] = *(const short8*)(lds1 + (m * 16 + n) * 80 + kb * 16);
    }
    #pragma unroll
    for (int m = 0; m < 4; ++m) {
        f32x4 p0 = __builtin_amdgcn_mfma_f32_16x16x32_bf16(a0[m], b1a, z, 0, 0, 0);
        acc0[m] = __builtin_amdgcn_mfma_f32_16x16x32_bf16(a0[m], b1b, p0, 0, 0, 0);
        f32x4 p1 = __builtin_amdgcn_mfma_f32_16x16x32_bf16(a1[m], b1a, z, 0, 0, 0);
        acc1[m] = __builtin_amdgcn_mfma_f32_16x16x32_bf16(a1[m], b1b, p1, 0, 0, 0);
    }

    // ---- layer 2
    #pragma unroll
    for (int m = 0; m < 4; ++m) {
        #pragma unroll
        for (int r = 0; r < 4; ++r) {
            const int row = m * 16 + kb * 4 + r;
            hp0[row * 20 + n] = hilo_pack(__sinf(acc0[m][r] + b1n));
            hp1[row * 20 + n] = hilo_pack(__sinf(acc1[m][r] + b1n));
        }
    }
    #pragma unroll
    for (int m = 0; m < 4; ++m) {
        a0[m] = *(const short8*)(lds0 + (m * 16 + n) * 80 + kb * 16);
        a1[m] = *(const short8*)(lds1 + (m * 16 + n) * 80 + kb * 16);
    }
    #pragma unroll
    for (int m = 0; m < 4; ++m) {
        f32x4 p0 = __builtin_amdgcn_mfma_f32_16x16x32_bf16(a0[m], b2a, z, 0, 0, 0);
        acc0[m] = __builtin_amdgcn_mfma_f32_16x16x32_bf16(a0[m], b2b, p0, 0, 0, 0);
        f32x4 p1 = __builtin_amdgcn_mfma_f32_16x16x32_bf16(a1[m], b2a, z, 0, 0, 0);
        acc1[m] = __builtin_amdgcn_mfma_f32_16x16x32_bf16(a1[m], b2b, p1, 0, 0, 0);
    }

    // ---- layer 3 (16->1) in f32: shuffle-reduce over the 16 n-lanes
    const int m2 = n >> 2, r2 = n & 3;
    float ov0 = 0.f, ov1 = 0.f;
    #pragma unroll
    for (int m = 0; m < 4; ++m) {
        #pragma unroll
        for (int r = 0; r < 4; ++r) {
            float v0 = __sinf(acc0[m][r] + b2n) * w3n;
            float v1 = __sinf(acc1[m][r] + b2n) * w3n;
            v0 += __shfl_xor(v0, 1);  v1 += __shfl_xor(v1, 1);
            v0 += __shfl_xor(v0, 2);  v1 += __shfl_xor(v1, 2);
            v0 += __shfl_xor(v0, 4);  v1 += __shfl_xor(v1, 4);
            v0 += __shfl_xor(v0, 8);  v1 += __shfl_xor(v1, 8);
            if (m == m2 && r == r2) { ov0 = v0; ov1 = v1; }
        }
    }
    const int row0 = m2 * 16 + kb * 4 + r2;
    const int g0 = wbase + 2 * row0;                 // tile0=even, tile1=odd pt
    if (g0 + 1 < N) {
        float2v o; o.x = ov0 + b3s; o.y = ov1 + b3s;
        __builtin_nontemporal_store(o, reinterpret_cast<float2v*>(out + g0));
    } else if (g0 < N) {
        out[g0] = ov0 + b3s;
    }
}

// ---- fallback: R1 fused kernel (known-good) for small ws
__global__ __launch_bounds__(256) void hashsiren_fused(
    const float* __restrict__ coords,
    const float* __restrict__ table,
    const float* __restrict__ W0, const float* __restrict__ b0,
    const float* __restrict__ W1, const float* __restrict__ b1,
    const float* __restrict__ W2, const float* __restrict__ b2,
    const float* __restrict__ W3, const float* __restrict__ b3,
    float* __restrict__ out, int N)
{
    __shared__ float sW0[384];
    __shared__ float sW1[256];
    __shared__ float sW2[256];
    __shared__ float sb0[16], sb1[16], sb2[16], sW3[16];
    __shared__ float sb3;

    const int t = threadIdx.x;
    for (int i = t; i < 384; i += 256) sW0[i] = W0[i];
    sW1[t] = W1[t];
    sW2[t] = W2[t];
    if (t < 16) { sb0[t] = b0[t]; sb1[t] = b1[t]; sb2[t] = b2[t]; sW3[t] = W3[t]; }
    if (t == 0) sb3 = b3[0];
    __syncthreads();

    const int idx = blockIdx.x * 256 + t;
    if (idx >= N) return;

    const float2 c = reinterpret_cast<const float2*>(coords)[idx];

    float2 hv00[6], hv10[6], hv01[6], hv11[6];
    float hwx[6], hwy[6];
    #pragma unroll
    for (int l = 0; l < 6; ++l) {
        const int res = 16 << (l + 6);
        const float px = c.x * (float)res;
        const float py = c.y * (float)res;
        const float fx = floorf(px), fy = floorf(py);
        hwx[l] = px - fx;
        hwy[l] = py - fy;
        const unsigned ux = (unsigned)(int)fx, uy = (unsigned)(int)fy;
        const unsigned hy0 = uy * PRIME_Y;
        const unsigned hy1 = (uy + 1u) * PRIME_Y;
        const float2* __restrict__ tl =
            reinterpret_cast<const float2*>(table) + (size_t)(l + 6) * TSIZE;
        hv00[l] = tl[(ux ^ hy0) & (TSIZE - 1u)];
        hv10[l] = tl[((ux + 1u) ^ hy0) & (TSIZE - 1u)];
        hv01[l] = tl[(ux ^ hy1) & (TSIZE - 1u)];
        hv11[l] = tl[((ux + 1u) ^ hy1) & (TSIZE - 1u)];
    }

    float enc[24];
    #pragma unroll
    for (int lvl = 0; lvl < 6; ++lvl) {
        const int res = 16 << lvl;
        const float px = c.x * (float)res;
        const float py = c.y * (float)res;
        const float fx = floorf(px), fy = floorf(py);
        const float wx = px - fx, wy = py - fy;
        const int ix = (int)fx, iy = (int)fy;
        const int stride = res + 1;
        const int base = ix + iy * stride;
        const float2* __restrict__ tl =
            reinterpret_cast<const float2*>(table) + (size_t)lvl * TSIZE;
        const float2 v00 = tl[base];
        const float2 v10 = tl[base + 1];
        const float2 v01 = tl[base + stride];
        const float2 v11 = tl[base + stride + 1];
        const float w00 = (1.0f - wx) * (1.0f - wy);
        const float w10 = wx * (1.0f - wy);
        const float w01 = (1.0f - wx) * wy;
        const float w11 = wx * wy;
        enc[2 * lvl]     = v00.x * w00 + v10.x * w10 + v01.x * w01 + v11.x * w11;
        enc[2 * lvl + 1] = v00.y * w00 + v10.y * w10 + v01.y * w01 + v11.y * w11;
    }
    #pragma unroll
    for (int l = 0; l < 6; ++l) {
        const float wx = hwx[l], wy = hwy[l];
        const float w00 = (1.0f - wx) * (1.0f - wy);
        const float w10 = wx * (1.0f - wy);
        const float w01 = (1.0f - wx) * wy;
        const float w11 = wx * wy;
        enc[2 * (l + 6)]     = hv00[l].x * w00 + hv10[l].x * w10 + hv01[l].x * w01 + hv11[l].x * w11;
        enc[2 * (l + 6) + 1] = hv00[l].y * w00 + hv10[l].y * w10 + hv01[l].y * w01 + hv11[l].y * w11;
    }

    float h0[16];
    #pragma unroll
    for (int j = 0; j < 16; ++j) {
        float aa = sb0[j];
        #pragma unroll
        for (int k = 0; k < 24; ++k) aa += enc[k] * sW0[k * 16 + j];
        h0[j] = __sinf(300.0f * aa);
    }
    float h1[16];
    #pragma unroll
    for (int j = 0; j < 16; ++j) {
        float aa = sb1[j];
        #pragma unroll
        for (int k = 0; k < 16; ++k) aa += h0[k] * sW1[k * 16 + j];
        h1[j] = __sinf(aa);
    }
    float h2[16];
    #pragma unroll
    for (int j = 0; j < 16; ++j) {
        float aa = sb2[j];
        #pragma unroll
        for (int k = 0; k < 16; ++k) aa += h1[k] * sW2[k * 16 + j];
        h2[j] = __sinf(aa);
    }
    float o = sb3;
    #pragma unroll
    for (int k = 0; k < 16; ++k) o += h2[k] * sW3[k];
    out[idx] = o;
}

extern "C" void kernel_launch(void* const* d_in, const int* in_sizes, int n_in,
                              void* d_out, int out_size, void* d_ws, size_t ws_size,
                              hipStream_t stream) {
    const float* coords = (const float*)d_in[0];
    const float* table  = (const float*)d_in[1];
    const float* W0 = (const float*)d_in[2];
    const float* b0 = (const float*)d_in[3];
    const float* W1 = (const float*)d_in[4];
    const float* b1 = (const float*)d_in[5];
    const float* W2 = (const float*)d_in[6];
    const float* b2 = (const float*)d_in[7];
    const float* W3 = (const float*)d_in[8];
    const float* b3 = (const float*)d_in[9];
    float* out = (float*)d_out;

    const int N = in_sizes[0] / 2;  // coords is [N,2]

    const size_t tab_w = (size_t)NHASH * TSIZE / 2;      // fp8 pairs, 12 MB
    const size_t enc_w = (size_t)NHASH * (size_t)N;      // 6 streams, 24 MB
    const size_t dns_w = (size_t)NDENSE_PAD;             // bf16 dup cells, 2.8 MB
    const size_t need = (tab_w + enc_w + dns_w * 2) * 4 + 6144;
    if (ws_size >= need && N >= 2) {
        unsigned* wtab8 = (unsigned*)d_ws;
        unsigned* wenc = wtab8 + tab_w;
        unsigned* wdense = wenc + enc_w;                 // uint2 cells: 2 words each
        uint4v* wfrag = (uint4v*)(wdense + dns_w * 2);
        convert_kernel<<<4096, 256, 0, stream>>>(table, wtab8, wdense,
                                                 W0, b0, W1, b1, W2, b2, W3, wfrag);
        const int bpl = (N + 1023) / 1024;   // blocks per level
        pass_all_kernel<<<NHASH * bpl, 256, 0, stream>>>(coords, wtab8, wenc, bpl, N);
        mlp_kernel<<<(N + 511) / 512, 256, 0, stream>>>(coords, wdense, wenc, wfrag,
                                                        b3, out, N);
    } else {
        const int block = 256;
        const int grid = (N + block - 1) / block;
        hashsiren_fused<<<grid, block, 0, stream>>>(coords, table,
                                                    W0, b0, W1, b1, W2, b2, W3, b3,
                                                    out, N);
    }
}

// Round 15
// 139.767 us; speedup vs baseline: 1.3196x; 1.0614x over previous
//
#include <hip/hip_runtime.h>
#include <math.h>

#define TSIZE (1u << 20)
#define PRIME_Y 2654435761u
#define NHASH 6   // hashed levels 6..11
#define NDENSE_CELLS 351462   // sum (res+1)^2, res=16..512
#define NDENSE_PAD   351488

typedef __attribute__((ext_vector_type(8))) short short8;     // bf16x8 MFMA frag
typedef __attribute__((ext_vector_type(4))) float f32x4;      // MFMA acc frag
typedef __attribute__((ext_vector_type(4))) float float4v;
typedef __attribute__((ext_vector_type(2))) float float2v;
typedef __attribute__((ext_vector_type(4))) unsigned uint4v;
typedef __attribute__((ext_vector_type(2))) unsigned uint2v;

__device__ __forceinline__ unsigned bf16rne(unsigned u) {
    return (u + 0x7fffu + ((u >> 16) & 1u)) >> 16;   // RNE to bf16 (in low 16)
}
__device__ __forceinline__ unsigned pack_bf16x2(float a, float b) {
    return (bf16rne(__float_as_uint(a)) & 0xffffu) | (bf16rne(__float_as_uint(b)) << 16);
}
__device__ __forceinline__ float2 unpack_bf16x2(unsigned u) {
    float2 r;
    r.x = __uint_as_float(u << 16);
    r.y = __uint_as_float(u & 0xffff0000u);
    return r;
}
__device__ __forceinline__ short f2bf(float x) {
    return (short)(bf16rne(__float_as_uint(x)) & 0xffffu);
}
__device__ __forceinline__ float bf2f(short h) {
    return __uint_as_float(((unsigned)(unsigned short)h) << 16);
}
// RTZ hi/lo split packed as {hi_bits | lo_bits<<16}
__device__ __forceinline__ unsigned hilo_pack(float v) {
    const unsigned uv = __float_as_uint(v);
    const float l = v - __uint_as_float(uv & 0xffff0000u);
    return (uv >> 16) | (__float_as_uint(l) & 0xffff0000u);
}

// ---- fp8 e4m3 with x2^13 pre-scale (hashed-table values +-1e-4 -> ~0.8).
__device__ __forceinline__ unsigned fp8e(float f) {
    const float v = f * 8192.0f;
    const unsigned a = __float_as_uint(v);
    const unsigned sign = (a >> 31) << 7;
    const unsigned mag = a & 0x7fffffffu;
    const unsigned r = mag + 0x7ffffu + ((mag >> 20) & 1u);
    int u = (int)(r >> 20) - (120 << 3);
    u = (u < 0) ? 0 : u;
    return (unsigned)u | sign;
}
__device__ __forceinline__ float fp8d(unsigned u8) {
    const unsigned bits = ((u8 & 0x80u) << 24) |
                          (((u8 & 0x7fu) << 20) + (107u << 23));
    return __uint_as_float(bits);
}
__device__ __forceinline__ float2 fp8d2(unsigned u16) {   // {x:lo8, y:hi8}
    float2 r;
    r.x = fp8d(u16 & 0xffu);
    r.y = fp8d((u16 >> 8) & 0xffu);
    return r;
}

// ---- pass 0: hashed tables f32 -> fp8-pair (2 MiB/level, L2-resident);
// dense tables -> QUAD bf16 cells (one 16B load = all 4 interp corners);
// block 0 builds MFMA B-fragments.
__global__ __launch_bounds__(256) void convert_kernel(
    const float* __restrict__ table, unsigned* __restrict__ wtab8,
    uint4v* __restrict__ wquad,
    const float* __restrict__ W0, const float* __restrict__ b0,
    const float* __restrict__ W1, const float* __restrict__ b1,
    const float* __restrict__ W2, const float* __restrict__ b2,
    const float* __restrict__ W3,
    uint4v* __restrict__ wfrag)
{
    if (blockIdx.x == 0 && threadIdx.x < 64) {
        const int lane = threadIdx.x;
        const int n = lane & 15;
        const int kb = lane >> 4;
        short8 bf0, b1a, b1b, b2a, b2b;
        #pragma unroll
        for (int j = 0; j < 8; ++j) {
            const int k = kb * 8 + j;
            bf0[j] = (k < 24) ? f2bf(W0[k * 16 + n]) : (short)0;
            const int i = k >> 1;
            const float w1 = W1[i * 16 + n];
            const float w2 = W2[i * 16 + n];
            const short w1h = f2bf(w1), w2h = f2bf(w2);
            b1a[j] = w1h;
            b2a[j] = w2h;
            b1b[j] = (k & 1) ? (short)0 : f2bf(w1 - bf2f(w1h));
            b2b[j] = (k & 1) ? (short)0 : f2bf(w2 - bf2f(w2h));
        }
        union { short8 s; uint4v u; } cv;
        cv.s = bf0; wfrag[0 * 64 + lane] = cv.u;
        cv.s = b1a; wfrag[1 * 64 + lane] = cv.u;
        cv.s = b1b; wfrag[2 * 64 + lane] = cv.u;
        cv.s = b2a; wfrag[3 * 64 + lane] = cv.u;
        cv.s = b2b; wfrag[4 * 64 + lane] = cv.u;
        float4v bb;
        bb.x = b0[n]; bb.y = b1[n]; bb.z = b2[n]; bb.w = W3[n];
        union { float4v f; uint4v u; } cf; cf.f = bb;
        wfrag[5 * 64 + lane] = cf.u;
    }
    // hashed levels -> fp8 pairs
    const size_t total4 = (size_t)NHASH * TSIZE / 2;   // float4 chunks (2 entries)
    const float4v* __restrict__ src =
        reinterpret_cast<const float4v*>(table + (size_t)6 * TSIZE * 2);
    for (size_t i = (size_t)blockIdx.x * 256 + threadIdx.x; i < total4;
         i += (size_t)gridDim.x * 256) {
        float4v v = __builtin_nontemporal_load(&src[i]);
        wtab8[i] = fp8e(v.x) | (fp8e(v.y) << 8) | (fp8e(v.z) << 16) | (fp8e(v.w) << 24);
    }
    // dense levels -> quad bf16 cells {v00, v10, v01, v11}
    const int DCUM[7] = {0, 289, 1378, 5603, 22244, 88293, 351462};
    for (int i = blockIdx.x * 256 + threadIdx.x; i < NDENSE_CELLS;
         i += gridDim.x * 256) {
        int lvl = 0;
        #pragma unroll
        for (int l = 1; l < 6; ++l) lvl += (i >= DCUM[l]);
        const int e = i - DCUM[lvl];
        const int stride = (16 << lvl) + 1;
        const int ey = e / stride;
        const int ex = e - ey * stride;
        const int ex1 = (ex + 1 < stride) ? ex + 1 : ex;   // clamp (unused cells)
        const int ey1 = (ey + 1 < stride) ? ey + 1 : ey;
        const float* __restrict__ dsrc = table + (size_t)lvl * TSIZE * 2u;
        const int e10 = ey * stride + ex1;
        const int e01 = ey1 * stride + ex;
        const int e11 = ey1 * stride + ex1;
        uint4v o;
        o.x = pack_bf16x2(dsrc[2 * e],   dsrc[2 * e + 1]);
        o.y = pack_bf16x2(dsrc[2 * e10], dsrc[2 * e10 + 1]);
        o.z = pack_bf16x2(dsrc[2 * e01], dsrc[2 * e01 + 1]);
        o.w = pack_bf16x2(dsrc[2 * e11], dsrc[2 * e11 + 1]);
        wquad[i] = o;
    }
}

// ---- fused hash passes: ONE launch, level = blockIdx / bpl (consecutive
// blocks share a level -> <=2 tables live per XCD L2 at any instant).
__global__ __launch_bounds__(256) void pass_all_kernel(
    const float* __restrict__ coords,
    const unsigned* __restrict__ wtab8,
    unsigned* __restrict__ wenc,
    int bpl, int N)
{
    const int lvl = blockIdx.x / bpl;
    const int gid = (blockIdx.x - lvl * bpl) * 256 + threadIdx.x;
    const int base = gid * 4;
    if (base >= N) return;
    const int res = 16 << (lvl + 6);
    const unsigned* __restrict__ tlp = wtab8 + ((size_t)lvl * TSIZE >> 1);  // u32 pairs
    const unsigned short* __restrict__ tl8 =
        reinterpret_cast<const unsigned short*>(tlp);
    unsigned* __restrict__ we = wenc + (size_t)lvl * N;

    if (base + 3 < N) {
        const float4v* __restrict__ c4 = reinterpret_cast<const float4v*>(coords);
        const float4v ca = __builtin_nontemporal_load(&c4[gid * 2]);
        const float4v cb = __builtin_nontemporal_load(&c4[gid * 2 + 1]);
        const float xs[4] = {ca.x, ca.z, cb.x, cb.z};
        const float ys[4] = {ca.y, ca.w, cb.y, cb.w};
        unsigned h00a[4], h01a[4], h10a[4], h11a[4], oddp[4];
        float wxs[4], wys[4];
        #pragma unroll
        for (int p = 0; p < 4; ++p) {
            const float px = xs[p] * (float)res;
            const float py = ys[p] * (float)res;
            const float fx = floorf(px), fy = floorf(py);
            wxs[p] = px - fx;
            wys[p] = py - fy;
            const unsigned ux = (unsigned)(int)fx, uy = (unsigned)(int)fy;
            const unsigned hy0 = uy * PRIME_Y;
            const unsigned hy1 = (uy + 1u) * PRIME_Y;
            h00a[p] = (ux ^ hy0) & (TSIZE - 1u);
            h01a[p] = (ux ^ hy1) & (TSIZE - 1u);
            h10a[p] = ((ux + 1u) ^ hy0) & (TSIZE - 1u);
            h11a[p] = ((ux + 1u) ^ hy1) & (TSIZE - 1u);
            oddp[p] = ux & 1u;
        }
        unsigned pr0[4], pr1[4];
        #pragma unroll
        for (int p = 0; p < 4; ++p) {
            pr0[p] = tlp[h00a[p] >> 1];
            pr1[p] = tlp[h01a[p] >> 1];
        }
        unsigned t10[4], t11[4];
        #pragma unroll
        for (int p = 0; p < 4; ++p) { t10[p] = 0u; t11[p] = 0u; }
        #pragma unroll
        for (int p = 0; p < 4; ++p) {
            if (oddp[p]) {
                t10[p] = tl8[h10a[p]];
                t11[p] = tl8[h11a[p]];
            }
        }
        uint4v r;
        #pragma unroll
        for (int p = 0; p < 4; ++p) {
            const unsigned s0 = h00a[p] & 1u;
            const unsigned s1 = h01a[p] & 1u;
            const unsigned e00 = s0 ? (pr0[p] >> 16) : (pr0[p] & 0xffffu);
            const unsigned e01 = s1 ? (pr1[p] >> 16) : (pr1[p] & 0xffffu);
            const unsigned e10 = oddp[p] ? t10[p]
                                         : (s0 ? (pr0[p] & 0xffffu) : (pr0[p] >> 16));
            const unsigned e11 = oddp[p] ? t11[p]
                                         : (s1 ? (pr1[p] & 0xffffu) : (pr1[p] >> 16));
            const float wx = wxs[p], wy = wys[p];
            const float w00 = (1.0f - wx) * (1.0f - wy);
            const float w10 = wx * (1.0f - wy);
            const float w01 = (1.0f - wx) * wy;
            const float w11 = wx * wy;
            const float2 f00 = fp8d2(e00);
            const float2 f10 = fp8d2(e10);
            const float2 f01 = fp8d2(e01);
            const float2 f11 = fp8d2(e11);
            const float e0 = f00.x * w00 + f10.x * w10 + f01.x * w01 + f11.x * w11;
            const float e1 = f00.y * w00 + f10.y * w10 + f01.y * w01 + f11.y * w11;
            r[p] = pack_bf16x2(e0, e1);
        }
        ((uint4v*)we)[gid] = r;   // normal store: enc stays cached for mlp
    } else {
        for (int p = 0; p < 4 && base + p < N; ++p) {
            const float2 c = reinterpret_cast<const float2*>(coords)[base + p];
            const float px = c.x * (float)res;
            const float py = c.y * (float)res;
            const float fx = floorf(px), fy = floorf(py);
            const float wx = px - fx, wy = py - fy;
            const unsigned ux = (unsigned)(int)fx, uy = (unsigned)(int)fy;
            const unsigned hy0 = uy * PRIME_Y;
            const unsigned hy1 = (uy + 1u) * PRIME_Y;
            const float2 v00 = fp8d2(tl8[(ux ^ hy0) & (TSIZE - 1u)]);
            const float2 v10 = fp8d2(tl8[((ux + 1u) ^ hy0) & (TSIZE - 1u)]);
            const float2 v01 = fp8d2(tl8[(ux ^ hy1) & (TSIZE - 1u)]);
            const float2 v11 = fp8d2(tl8[((ux + 1u) ^ hy1) & (TSIZE - 1u)]);
            const float w00 = (1.0f - wx) * (1.0f - wy);
            const float w10 = wx * (1.0f - wy);
            const float w01 = (1.0f - wx) * wy;
            const float w11 = wx * wy;
            const float e0 = v00.x * w00 + v10.x * w10 + v01.x * w01 + v11.x * w11;
            const float e1 = v00.y * w00 + v10.y * w10 + v01.y * w01 + v11.y * w11;
            we[base + p] = pack_bf16x2(e0, e1);
        }
    }
}

// ---- stage one point's 12 packed enc words as an MFMA A-row (K 24->32)
__device__ __forceinline__ void stage_row(char* ldsw, int lane, const unsigned* u) {
    uint4v* rowp = (uint4v*)(ldsw + lane * 80);
    uint4v r0; r0.x = u[0]; r0.y = u[1]; r0.z = u[2]; r0.w = u[3];
    uint4v r1; r1.x = u[4]; r1.y = u[5]; r1.z = u[6]; r1.w = u[7];
    uint4v r2; r2.x = u[8]; r2.y = u[9]; r2.z = u[10]; r2.w = u[11];
    uint4v r3; r3.x = 0u; r3.y = 0u; r3.z = 0u; r3.w = 0u;  // keep: no NaN*0
    rowp[0] = r0; rowp[1] = r1; rowp[2] = r2; rowp[3] = r3;
}

// ---- final: dense (quad bf16 cells, ONE 16B load per level per point) +
// hashed enc streams + MFMA MLP. Adjacent-point pairing, no barriers.
__global__ __launch_bounds__(256) void mlp_kernel(
    const float* __restrict__ coords,
    const uint4v* __restrict__ wquad,
    const unsigned* __restrict__ wenc,
    const uint4v* __restrict__ wfrag,
    const float* __restrict__ b3p,
    float* __restrict__ out, int N)
{
    __shared__ char lds[40960];             // 4 waves * 2 tiles * 5120 B
    const int t = threadIdx.x;
    const int lane = t & 63;
    const int wv = t >> 6;
    const int n = lane & 15;
    const int kb = lane >> 4;
    char* lds0 = lds + wv * 10240;
    char* lds1 = lds0 + 5120;

    union { short8 s; uint4v u; } w0u, w1au, w1bu, w2au, w2bu;
    w0u.u  = wfrag[0 * 64 + lane];
    w1au.u = wfrag[1 * 64 + lane];
    w1bu.u = wfrag[2 * 64 + lane];
    w2au.u = wfrag[3 * 64 + lane];
    w2bu.u = wfrag[4 * 64 + lane];
    const short8 bf0 = w0u.s, b1a = w1au.s, b1b = w1bu.s, b2a = w2au.s, b2b = w2bu.s;
    union { float4v f; uint4v u; } cf;
    cf.u = wfrag[5 * 64 + lane];
    const float b0n = cf.f.x, b1n = cf.f.y, b2n = cf.f.z, w3n = cf.f.w;
    const float b3s = b3p[0];

    const int wbase = blockIdx.x * 512 + wv * 128;   // 4 waves * 128 pts
    int i0 = wbase + 2 * lane;
    if (i0 > N - 2) i0 = (N - 2) & ~1;               // clamp, keep even

    // 6 paired enc loads ({even,odd} in one aligned uint2)
    unsigned u0[12], u1[12];
    #pragma unroll
    for (int l = 0; l < NHASH; ++l) {
        const uint2v ev = *reinterpret_cast<const uint2v*>(wenc + (size_t)l * N + i0);
        u0[6 + l] = ev.x;
        u1[6 + l] = ev.y;
    }
    // paired coords: one float4 covers both points
    const float4v cc = reinterpret_cast<const float4v*>(coords)[i0 >> 1];
    const float2 cA = {cc.x, cc.y};
    const float2 cB = {cc.z, cc.w};

    const int DC[6] = {0, 289, 1378, 5603, 22244, 88293};
    #pragma unroll
    for (int lvl = 0; lvl < 6; ++lvl) {
        const int res = 16 << lvl;
        const int stride = res + 1;
        const uint4v* __restrict__ td = wquad + DC[lvl];
        {
            const float px = cA.x * (float)res;
            const float py = cA.y * (float)res;
            const float fx = floorf(px), fy = floorf(py);
            const float wx = px - fx, wy = py - fy;
            const int b = (int)fx + (int)fy * stride;
            const uint4v q = td[b];                  // all 4 corners, one load
            const float2 v00 = unpack_bf16x2(q.x);
            const float2 v10 = unpack_bf16x2(q.y);
            const float2 v01 = unpack_bf16x2(q.z);
            const float2 v11 = unpack_bf16x2(q.w);
            const float w00 = (1.0f - wx) * (1.0f - wy);
            const float w10 = wx * (1.0f - wy);
            const float w01 = (1.0f - wx) * wy;
            const float w11 = wx * wy;
            u0[lvl] = pack_bf16x2(v00.x * w00 + v10.x * w10 + v01.x * w01 + v11.x * w11,
                                  v00.y * w00 + v10.y * w10 + v01.y * w01 + v11.y * w11);
        }
        {
            const float px = cB.x * (float)res;
            const float py = cB.y * (float)res;
            const float fx = floorf(px), fy = floorf(py);
            const float wx = px - fx, wy = py - fy;
            const int b = (int)fx + (int)fy * stride;
            const uint4v q = td[b];
            const float2 v00 = unpack_bf16x2(q.x);
            const float2 v10 = unpack_bf16x2(q.y);
            const float2 v01 = unpack_bf16x2(q.z);
            const float2 v11 = unpack_bf16x2(q.w);
            const float w00 = (1.0f - wx) * (1.0f - wy);
            const float w10 = wx * (1.0f - wy);
            const float w01 = (1.0f - wx) * wy;
            const float w11 = wx * wy;
            u1[lvl] = pack_bf16x2(v00.x * w00 + v10.x * w10 + v01.x * w01 + v11.x * w11,
                                  v00.y * w00 + v10.y * w10 + v01.y * w01 + v11.y * w11);
        }
    }

    stage_row(lds0, lane, u0);
    stage_row(lds1, lane, u1);

    short8 a0[4], a1[4];
    #pragma unroll
    for (int m = 0; m < 4; ++m) {
        a0[m] = *(const short8*)(lds0 + (m * 16 + n) * 80 + kb * 16);
        a1[m] = *(const short8*)(lds1 + (m * 16 + n) * 80 + kb * 16);
    }

    const f32x4 z = {0.f, 0.f, 0.f, 0.f};
    f32x4 acc0[4], acc1[4];
    #pragma unroll
    for (int m = 0; m < 4; ++m) {
        acc0[m] = __builtin_amdgcn_mfma_f32_16x16x32_bf16(a0[m], bf0, z, 0, 0, 0);
        acc1[m] = __builtin_amdgcn_mfma_f32_16x16x32_bf16(a1[m], bf0, z, 0, 0, 0);
    }

    unsigned* hp0 = (unsigned*)lds0;   // rows of 20 words; word n = {hi|lo<<16}
    unsigned* hp1 = (unsigned*)lds1;

    // ---- layer 1
    #pragma unroll
    for (int m = 0; m < 4; ++m) {
        #pragma unroll
        for (int r = 0; r < 4; ++r) {
            const int row = m * 16 + kb * 4 + r;
            hp0[row * 20 + n] = hilo_pack(__sinf(300.0f * (acc0[m][r] + b0n)));
            hp1[row * 20 + n] = hilo_pack(__sinf(300.0f * (acc1[m][r] + b0n)));
        }
    }
    #pragma unroll
    for (int m = 0; m < 4; ++m) {
        a0[m] = *(const short8*)(lds0 + (m * 16 + n) * 80 + kb * 16);
        a1[m] = *(const short8*)(lds1 + (m * 16 + n) * 80 + kb * 16);
    }
    #pragma unroll
    for (int m = 0; m < 4; ++m) {
        f32x4 p0 = __builtin_amdgcn_mfma_f32_16x16x32_bf16(a0[m], b1a, z, 0, 0, 0);
        acc0[m] = __builtin_amdgcn_mfma_f32_16x16x32_bf16(a0[m], b1b, p0, 0, 0, 0);
        f32x4 p1 = __builtin_amdgcn_mfma_f32_16x16x32_bf16(a1[m], b1a, z, 0, 0, 0);
        acc1[m] = __builtin_amdgcn_mfma_f32_16x16x32_bf16(a1[m], b1b, p1, 0, 0, 0);
    }

    // ---- layer 2
    #pragma unroll
    for (int m = 0; m < 4; ++m) {
        #pragma unroll
        for (int r = 0; r < 4; ++r) {
            const int row = m * 16 + kb * 4 + r;
            hp0[row * 20 + n] = hilo_pack(__sinf(acc0[m][r] + b1n));
            hp1[row * 20 + n] = hilo_pack(__sinf(acc1[m][r] + b1n));
        }
    }
    #pragma unroll
    for (int m = 0; m < 4; ++m) {
        a0[m] = *(const short8*)(lds0 + (m * 16 + n) * 80 + kb * 16);
        a1[m] = *(const short8*)(lds1 + (m * 16 + n) * 80 + kb * 16);
    }
    #pragma unroll
    for (int m = 0; m < 4; ++m) {
        f32x4 p0 = __builtin_amdgcn_mfma_f32_16x16x32_bf16(a0[m], b2a, z, 0, 0, 0);
        acc0[m] = __builtin_amdgcn_mfma_f32_16x16x32_bf16(a0[m], b2b, p0, 0, 0, 0);
        f32x4 p1 = __builtin_amdgcn_mfma_f32_16x16x32_bf16(a1[m], b2a, z, 0, 0, 0);
        acc1[m] = __builtin_amdgcn_mfma_f32_16x16x32_bf16(a1[m], b2b, p1, 0, 0, 0);
    }

    // ---- layer 3 (16->1) in f32: shuffle-reduce over the 16 n-lanes
    const int m2 = n >> 2, r2 = n & 3;
    float ov0 = 0.f, ov1 = 0.f;
    #pragma unroll
    for (int m = 0; m < 4; ++m) {
        #pragma unroll
        for (int r = 0; r < 4; ++r) {
            float v0 = __sinf(acc0[m][r] + b2n) * w3n;
            float v1 = __sinf(acc1[m][r] + b2n) * w3n;
            v0 += __shfl_xor(v0, 1);  v1 += __shfl_xor(v1, 1);
            v0 += __shfl_xor(v0, 2);  v1 += __shfl_xor(v1, 2);
            v0 += __shfl_xor(v0, 4);  v1 += __shfl_xor(v1, 4);
            v0 += __shfl_xor(v0, 8);  v1 += __shfl_xor(v1, 8);
            if (m == m2 && r == r2) { ov0 = v0; ov1 = v1; }
        }
    }
    const int row0 = m2 * 16 + kb * 4 + r2;
    const int g0 = wbase + 2 * row0;                 // tile0=even, tile1=odd pt
    if (g0 + 1 < N) {
        float2v o; o.x = ov0 + b3s; o.y = ov1 + b3s;
        __builtin_nontemporal_store(o, reinterpret_cast<float2v*>(out + g0));
    } else if (g0 < N) {
        out[g0] = ov0 + b3s;
    }
}

// ---- fallback: R1 fused kernel (known-good) for small ws
__global__ __launch_bounds__(256) void hashsiren_fused(
    const float* __restrict__ coords,
    const float* __restrict__ table,
    const float* __restrict__ W0, const float* __restrict__ b0,
    const float* __restrict__ W1, const float* __restrict__ b1,
    const float* __restrict__ W2, const float* __restrict__ b2,
    const float* __restrict__ W3, const float* __restrict__ b3,
    float* __restrict__ out, int N)
{
    __shared__ float sW0[384];
    __shared__ float sW1[256];
    __shared__ float sW2[256];
    __shared__ float sb0[16], sb1[16], sb2[16], sW3[16];
    __shared__ float sb3;

    const int t = threadIdx.x;
    for (int i = t; i < 384; i += 256) sW0[i] = W0[i];
    sW1[t] = W1[t];
    sW2[t] = W2[t];
    if (t < 16) { sb0[t] = b0[t]; sb1[t] = b1[t]; sb2[t] = b2[t]; sW3[t] = W3[t]; }
    if (t == 0) sb3 = b3[0];
    __syncthreads();

    const int idx = blockIdx.x * 256 + t;
    if (idx >= N) return;

    const float2 c = reinterpret_cast<const float2*>(coords)[idx];

    float2 hv00[6], hv10[6], hv01[6], hv11[6];
    float hwx[6], hwy[6];
    #pragma unroll
    for (int l = 0; l < 6; ++l) {
        const int res = 16 << (l + 6);
        const float px = c.x * (float)res;
        const float py = c.y * (float)res;
        const float fx = floorf(px), fy = floorf(py);
        hwx[l] = px - fx;
        hwy[l] = py - fy;
        const unsigned ux = (unsigned)(int)fx, uy = (unsigned)(int)fy;
        const unsigned hy0 = uy * PRIME_Y;
        const unsigned hy1 = (uy + 1u) * PRIME_Y;
        const float2* __restrict__ tl =
            reinterpret_cast<const float2*>(table) + (size_t)(l + 6) * TSIZE;
        hv00[l] = tl[(ux ^ hy0) & (TSIZE - 1u)];
        hv10[l] = tl[((ux + 1u) ^ hy0) & (TSIZE - 1u)];
        hv01[l] = tl[(ux ^ hy1) & (TSIZE - 1u)];
        hv11[l] = tl[((ux + 1u) ^ hy1) & (TSIZE - 1u)];
    }

    float enc[24];
    #pragma unroll
    for (int lvl = 0; lvl < 6; ++lvl) {
        const int res = 16 << lvl;
        const float px = c.x * (float)res;
        const float py = c.y * (float)res;
        const float fx = floorf(px), fy = floorf(py);
        const float wx = px - fx, wy = py - fy;
        const int ix = (int)fx, iy = (int)fy;
        const int stride = res + 1;
        const int base = ix + iy * stride;
        const float2* __restrict__ tl =
            reinterpret_cast<const float2*>(table) + (size_t)lvl * TSIZE;
        const float2 v00 = tl[base];
        const float2 v10 = tl[base + 1];
        const float2 v01 = tl[base + stride];
        const float2 v11 = tl[base + stride + 1];
        const float w00 = (1.0f - wx) * (1.0f - wy);
        const float w10 = wx * (1.0f - wy);
        const float w01 = (1.0f - wx) * wy;
        const float w11 = wx * wy;
        enc[2 * lvl]     = v00.x * w00 + v10.x * w10 + v01.x * w01 + v11.x * w11;
        enc[2 * lvl + 1] = v00.y * w00 + v10.y * w10 + v01.y * w01 + v11.y * w11;
    }
    #pragma unroll
    for (int l = 0; l < 6; ++l) {
        const float wx = hwx[l], wy = hwy[l];
        const float w00 = (1.0f - wx) * (1.0f - wy);
        const float w10 = wx * (1.0f - wy);
        const float w01 = (1.0f - wx) * wy;
        const float w11 = wx * wy;
        enc[2 * (l + 6)]     = hv00[l].x * w00 + hv10[l].x * w10 + hv01[l].x * w01 + hv11[l].x * w11;
        enc[2 * (l + 6) + 1] = hv00[l].y * w00 + hv10[l].y * w10 + hv01[l].y * w01 + hv11[l].y * w11;
    }

    float h0[16];
    #pragma unroll
    for (int j = 0; j < 16; ++j) {
        float aa = sb0[j];
        #pragma unroll
        for (int k = 0; k < 24; ++k) aa += enc[k] * sW0[k * 16 + j];
        h0[j] = __sinf(300.0f * aa);
    }
    float h1[16];
    #pragma unroll
    for (int j = 0; j < 16; ++j) {
        float aa = sb1[j];
        #pragma unroll
        for (int k = 0; k < 16; ++k) aa += h0[k] * sW1[k * 16 + j];
        h1[j] = __sinf(aa);
    }
    float h2[16];
    #pragma unroll
    for (int j = 0; j < 16; ++j) {
        float aa = sb2[j];
        #pragma unroll
        for (int k = 0; k < 16; ++k) aa += h1[k] * sW2[k * 16 + j];
        h2[j] = __sinf(aa);
    }
    float o = sb3;
    #pragma unroll
    for (int k = 0; k < 16; ++k) o += h2[k] * sW3[k];
    out[idx] = o;
}

extern "C" void kernel_launch(void* const* d_in, const int* in_sizes, int n_in,
                              void* d_out, int out_size, void* d_ws, size_t ws_size,
                              hipStream_t stream) {
    const float* coords = (const float*)d_in[0];
    const float* table  = (const float*)d_in[1];
    const float* W0 = (const float*)d_in[2];
    const float* b0 = (const float*)d_in[3];
    const float* W1 = (const float*)d_in[4];
    const float* b1 = (const float*)d_in[5];
    const float* W2 = (const float*)d_in[6];
    const float* b2 = (const float*)d_in[7];
    const float* W3 = (const float*)d_in[8];
    const float* b3 = (const float*)d_in[9];
    float* out = (float*)d_out;

    const int N = in_sizes[0] / 2;  // coords is [N,2]

    const size_t tab_w = (size_t)NHASH * TSIZE / 2;      // fp8 pairs, 12 MB
    const size_t enc_w = (size_t)NHASH * (size_t)N;      // 6 streams, 24 MB
    const size_t need = (tab_w + enc_w) * 4 + (size_t)NDENSE_PAD * 16 + 6144;
    if (ws_size >= need && N >= 2) {
        unsigned* wtab8 = (unsigned*)d_ws;
        unsigned* wenc = wtab8 + tab_w;
        uint4v* wquad = (uint4v*)(wenc + enc_w);         // 16B quad cells
        uint4v* wfrag = wquad + NDENSE_PAD;
        convert_kernel<<<4096, 256, 0, stream>>>(table, wtab8, wquad,
                                                 W0, b0, W1, b1, W2, b2, W3, wfrag);
        const int bpl = (N + 1023) / 1024;   // blocks per level
        pass_all_kernel<<<NHASH * bpl, 256, 0, stream>>>(coords, wtab8, wenc, bpl, N);
        mlp_kernel<<<(N + 511) / 512, 256, 0, stream>>>(coords, wquad, wenc, wfrag,
                                                        b3, out, N);
    } else {
        const int block = 256;
        const int grid = (N + block - 1) / block;
        hashsiren_fused<<<grid, block, 0, stream>>>(coords, table,
                                                    W0, b0, W1, b1, W2, b2, W3, b3,
                                                    out, N);
    }
}